// Round 19
// baseline (822.960 us; speedup 1.0000x reference)
//
#include <hip/hip_runtime.h>
#include <math.h>

#define DEPTH 4
#define DMODEL 512
#define DH 64
#define MF 256
#define FFD 2048
#define SEQN 4096
#define NROWS 8192

// padded pitches (elements) — break power-of-2 HBM strides
#define LDY 544      // ybf / abuf rows (512+32)
#define LDQ 1056     // qkvb rows (1024+32)
#define LDF 2080     // ffmid rows (2048+32)
#define LDKV 4160    // KPt / Vt rows (4096+64)

typedef __bf16 bf16_t;
typedef bf16_t bf16x8 __attribute__((ext_vector_type(8)));
typedef bf16_t bf16x4 __attribute__((ext_vector_type(4)));
typedef bf16_t bf16x2 __attribute__((ext_vector_type(2)));
typedef float f32x4v __attribute__((ext_vector_type(4)));

static constexpr float DN = 0.35355339059327373f;   // 64^-0.25
static constexpr float RATIO = 0.0625f;             // 256^-0.5
static constexpr float EPSK = 1e-4f;

__device__ __forceinline__ float gelu_fast(float x) {
    float z2 = x * (1.5957691216f + 0.0713548162f * x * x);
    return x / (1.0f + __expf(-z2));
}

#define AS1(p) ((const __attribute__((address_space(1))) void*)(p))
#define AS3(p) ((__attribute__((address_space(3))) void*)(p))

template <int N> __device__ __forceinline__ void wait_vmcnt() {
    if constexpr (N == 0) asm volatile("s_waitcnt vmcnt(0)" ::: "memory");
    else if constexpr (N == 1) asm volatile("s_waitcnt vmcnt(1)" ::: "memory");
    else if constexpr (N == 2) asm volatile("s_waitcnt vmcnt(2)" ::: "memory");
    else if constexpr (N == 3) asm volatile("s_waitcnt vmcnt(3)" ::: "memory");
    else if constexpr (N == 4) asm volatile("s_waitcnt vmcnt(4)" ::: "memory");
    else if constexpr (N == 5) asm volatile("s_waitcnt vmcnt(5)" ::: "memory");
    else if constexpr (N == 6) asm volatile("s_waitcnt vmcnt(6)" ::: "memory");
    else if constexpr (N == 8) asm volatile("s_waitcnt vmcnt(8)" ::: "memory");
    else asm volatile("s_waitcnt vmcnt(12)" ::: "memory");
}

// ---------------- LayerNorm -> bf16 (pitch LDY) ----------------
__global__ __launch_bounds__(256) void ln_kernel(const float* __restrict__ h,
                                                 const float* __restrict__ g,
                                                 const float* __restrict__ b,
                                                 bf16_t* __restrict__ y) {
    int row = blockIdx.x, tid = threadIdx.x;
    const float* hr = h + (size_t)row * DMODEL;
    float v0 = hr[tid], v1 = hr[tid + 256];
    __shared__ float s_sum[256], s_sq[256];
    s_sum[tid] = v0 + v1;
    s_sq[tid] = v0 * v0 + v1 * v1;
    __syncthreads();
    for (int off = 128; off > 0; off >>= 1) {
        if (tid < off) { s_sum[tid] += s_sum[tid + off]; s_sq[tid] += s_sq[tid + off]; }
        __syncthreads();
    }
    float mu = s_sum[0] * (1.0f / DMODEL);
    float var = s_sq[0] * (1.0f / DMODEL) - mu * mu;
    float rstd = rsqrtf(var + 1e-5f);
    bf16_t* yr = y + (size_t)row * LDY;
    yr[tid]       = (bf16_t)((v0 - mu) * rstd * g[tid] + b[tid]);
    yr[tid + 256] = (bf16_t)((v1 - mu) * rstd * g[tid + 256] + b[tid + 256]);
}

// ---------------- fused: hout = hin + P; LayerNorm -> bf16 (pitch LDY) ----------------
__global__ __launch_bounds__(256) void ln_add_kernel(const float* __restrict__ hin,
                                                     float* __restrict__ hout,
                                                     const bf16_t* __restrict__ p,
                                                     const float* __restrict__ g,
                                                     const float* __restrict__ b,
                                                     bf16_t* __restrict__ y) {
    int row = blockIdx.x, tid = threadIdx.x;
    const float* hr = hin + (size_t)row * DMODEL;
    const bf16_t* pr = p + (size_t)row * DMODEL;
    float2 hv = *(const float2*)(hr + 2 * tid);
    bf16x2 pv = *(const bf16x2*)(pr + 2 * tid);
    float v0 = hv.x + (float)pv[0];
    float v1 = hv.y + (float)pv[1];
    float2 outv; outv.x = v0; outv.y = v1;
    *(float2*)(hout + (size_t)row * DMODEL + 2 * tid) = outv;
    __shared__ float s_sum[256], s_sq[256];
    s_sum[tid] = v0 + v1;
    s_sq[tid] = v0 * v0 + v1 * v1;
    __syncthreads();
    for (int off = 128; off > 0; off >>= 1) {
        if (tid < off) { s_sum[tid] += s_sum[tid + off]; s_sq[tid] += s_sq[tid + off]; }
        __syncthreads();
    }
    float mu = s_sum[0] * (1.0f / DMODEL);
    float var = s_sq[0] * (1.0f / DMODEL) - mu * mu;
    float rstd = rsqrtf(var + 1e-5f);
    bf16x2 ov;
    ov[0] = (bf16_t)((v0 - mu) * rstd * g[2 * tid] + b[2 * tid]);
    ov[1] = (bf16_t)((v1 - mu) * rstd * g[2 * tid + 1] + b[2 * tid + 1]);
    *(bf16x2*)(y + (size_t)row * LDY + 2 * tid) = ov;
}

// ---------------- tail: h += P (bf16, pitch 512) ----------------
__global__ __launch_bounds__(256) void add_kernel(float* __restrict__ h,
                                                  const bf16_t* __restrict__ p) {
    size_t i = ((size_t)blockIdx.x * 256 + threadIdx.x) * 4;
    float4 hv = *(const float4*)(h + i);
    bf16x4 pv = *(const bf16x4*)(p + i);
    hv.x += (float)pv[0]; hv.y += (float)pv[1];
    hv.z += (float)pv[2]; hv.w += (float)pv[3];
    *(float4*)(h + i) = hv;
}

// ---------------- weight transpose+convert with padded pitches ----------------
// slot layout (elems): wq@0 (1536x544), wo@835584 (512x544), w1@1114112 (2048x544),
//                      w2@2228224 (512x2080); slot stride 3407872 elems
__global__ __launch_bounds__(256) void wconv_all(const float* __restrict__ Wqkv,
                                                 const float* __restrict__ Wo,
                                                 const float* __restrict__ Wff1,
                                                 const float* __restrict__ Wff2,
                                                 bf16_t* __restrict__ wslot) {
    __shared__ float t[32][33];
    int layer = blockIdx.y;
    int bid = blockIdx.x;
    const float* W; bf16_t* Wt; int N, nx, lb, pitch;
    bf16_t* slot = wslot + (size_t)layer * 3407872;
    if (bid < 768)       { W = Wqkv + (size_t)layer * 786432;  Wt = slot;           N = 1536; nx = 48; lb = bid;        pitch = 544; }
    else if (bid < 1024) { W = Wo   + (size_t)layer * 262144;  Wt = slot + 835584;  N = 512;  nx = 16; lb = bid - 768;  pitch = 544; }
    else if (bid < 2048) { W = Wff1 + (size_t)layer * 1048576; Wt = slot + 1114112; N = 2048; nx = 64; lb = bid - 1024; pitch = 544; }
    else                 { W = Wff2 + (size_t)layer * 1048576; Wt = slot + 2228224; N = 512;  nx = 16; lb = bid - 2048; pitch = 2080; }
    int n0 = (lb % nx) * 32, k0 = (lb / nx) * 32;
    int tx = threadIdx.x & 31, ty = threadIdx.x >> 5;
#pragma unroll
    for (int i = 0; i < 32; i += 8)
        t[ty + i][tx] = W[(size_t)(k0 + ty + i) * N + n0 + tx];
    __syncthreads();
#pragma unroll
    for (int i = 0; i < 32; i += 8)
        Wt[(size_t)(n0 + ty + i) * pitch + k0 + tx] = (bf16_t)t[tx][ty + i];
}

// ---------------- proj -> bf16 ----------------
__global__ __launch_bounds__(256) void pconv_kernel(const float* __restrict__ proj,
                                                    bf16_t* __restrict__ projb) {
    int i = (blockIdx.x * 256 + threadIdx.x) * 4;
    float4 v = *(const float4*)(proj + i);
    bf16x4 o;
    o[0] = (bf16_t)v.x; o[1] = (bf16_t)v.y; o[2] = (bf16_t)v.z; o[3] = (bf16_t)v.w;
    *(bf16x4*)(projb + i) = o;
}

// ---------------- 128x64 BK=32 P=3 pipelined MFMA GEMM, runtime pitches ----------------
template <int BM, int BN, int BK, int P, int ACT, int WB, int QKVE>
__global__ __launch_bounds__(256) void gemm_pipe(const bf16_t* __restrict__ A,
                                                 const bf16_t* __restrict__ Bt,
                                                 const float* __restrict__ bias,
                                                 bf16_t* __restrict__ Cb,
                                                 bf16_t* __restrict__ Vt,
                                                 int K, int lda, int ldb, int ldc) {
    static_assert(BK == 32, "BK fixed at 32 (KS==1)");
    constexpr int MR = BM / 2 / 16;
    constexpr int NR = BN / 2 / 16;
    constexpr int CH = BK / 8;
    constexpr int SWZ = CH - 1;
    constexpr int TILE = (BM + BN) * BK;
    constexpr int L = TILE / 8 / 256;
    __shared__ __attribute__((aligned(16))) bf16_t smem[P * TILE];
    int tid = threadIdx.x;
    int wv = tid >> 6, ln = tid & 63;
    int gx = gridDim.x;
    int lin = blockIdx.y * gx + blockIdx.x;
    int per = (gx * gridDim.y) >> 3;
    int orig = (lin & 7) * per + (lin >> 3);
    int m0 = (orig / gx) * BM, n0 = (orig % gx) * BN;
    int wr = (wv >> 1) * (MR * 16), wc = (wv & 1) * (NR * 16);
    int lr = ln & 15, kq8 = ln >> 4;
    int nsteps = K / BK;

    const bf16_t* gsrc[L];
    int ldst[L];
#pragma unroll
    for (int i = 0; i < L; i++) {
        int c = i * 256 + tid;
        int cb = i * 256 + (tid & ~63);
        bool inA = (c < BM * CH);
        int cc = inA ? c : c - BM * CH;
        int row = cc / CH, ch = cc % CH;
        const bf16_t* mat = inA ? A : Bt;
        int r0 = inA ? m0 : n0;
        int ld = inA ? lda : ldb;
        int chs = ch ^ ((row ^ (row >> 2)) & SWZ);
        gsrc[i] = mat + (size_t)(r0 + row) * ld + chs * 8;
        ldst[i] = cb * 8;
    }
    auto stage = [&](int tile, int sb) {
        int k0 = tile * BK;
        bf16_t* dst = smem + sb * TILE;
#pragma unroll
        for (int i = 0; i < L; i++)
            __builtin_amdgcn_global_load_lds(AS1(gsrc[i] + k0), AS3(dst + ldst[i]), 16, 0, 0);
    };

    int aoff[MR], boff[NR];
#pragma unroll
    for (int m = 0; m < MR; m++) {
        int row = wr + m * 16 + lr;
        aoff[m] = (row * CH + (kq8 ^ ((row ^ (row >> 2)) & SWZ))) * 8;
    }
#pragma unroll
    for (int n = 0; n < NR; n++) {
        int row = wc + n * 16 + lr;
        boff[n] = BM * BK + (row * CH + (kq8 ^ ((row ^ (row >> 2)) & SWZ))) * 8;
    }

    f32x4v acc[MR][NR] = {};
#pragma unroll
    for (int p = 0; p < P - 1; ++p) stage(p, p);

    int cur = 0;
    for (int t = 0; t < nsteps; ++t) {
        int rem = nsteps - 1 - t;
        if (rem >= P - 2) wait_vmcnt<(P - 2) * L>();
        else if constexpr (P >= 4) {
            if (rem == 1) wait_vmcnt<L>(); else wait_vmcnt<0>();
        } else wait_vmcnt<0>();
        __builtin_amdgcn_s_barrier();
        asm volatile("" ::: "memory");
        if (t + P - 1 < nsteps) {
            int sb = cur - 1; if (sb < 0) sb = P - 1;
            stage(t + P - 1, sb);
        }
        const bf16_t* base = smem + cur * TILE;
        bf16x8 af[MR], bfr[NR];
#pragma unroll
        for (int m = 0; m < MR; m++) af[m] = *(const bf16x8*)&base[aoff[m]];
#pragma unroll
        for (int n = 0; n < NR; n++) bfr[n] = *(const bf16x8*)&base[boff[n]];
        __builtin_amdgcn_s_setprio(1);
#pragma unroll
        for (int m = 0; m < MR; m++)
#pragma unroll
            for (int n = 0; n < NR; n++)
                acc[m][n] = __builtin_amdgcn_mfma_f32_16x16x32_bf16(af[m], bfr[n], acc[m][n], 0, 0, 0);
        __builtin_amdgcn_s_setprio(0);
        cur = (cur + 1 == P) ? 0 : cur + 1;
    }
    int rq = (ln >> 4) * 4;
    // ---- coalesced bf16 epilogue through LDS (tile BM x BN) ----
    __syncthreads();
    bf16_t* T = smem;
    constexpr int S = BN + 8;
#pragma unroll
    for (int n = 0; n < NR; n++) {
        int col = wc + n * 16 + lr;
        float bcol = bias[n0 + col];
#pragma unroll
        for (int m = 0; m < MR; m++) {
#pragma unroll
            for (int r = 0; r < 4; r++) {
                int row = wr + m * 16 + rq + r;
                float v = acc[m][n][r] + bcol;
                if (ACT == 1) v = gelu_fast(v);
                int cs = (col & 7) | ((((col >> 3) ^ (row >> 3)) & (BN / 8 - 1)) << 3);
                T[row * S + cs] = (bf16_t)v;
            }
        }
    }
    __syncthreads();
    if (!QKVE || n0 < 1024) {
#pragma unroll
        for (int i = 0; i < BM * BN / 8 / 256; i++) {
            int e = i * 2048 + tid * 8;
            int row = e / BN, c0 = e % BN;
            int ch = ((c0 >> 3) ^ (row >> 3)) & (BN / 8 - 1);
            bf16x8 v = *(const bf16x8*)&T[row * S + ch * 8];
            *(bf16x8*)&Cb[(size_t)(m0 + row) * ldc + n0 + c0] = v;
        }
    } else {
        // V region -> Vt transposed, 16B stores along n (pitch LDKV)
#pragma unroll
        for (int i = 0; i < BM * BN / 8 / 256; i++) {
            int u = i * 256 + tid;
            int d = u & (BN - 1), nb8 = (u / BN) * 8;
            bf16x8 v;
#pragma unroll
            for (int j = 0; j < 8; j++) {
                int row = nb8 + j;
                int cs = (d & 7) | ((((d >> 3) ^ (row >> 3)) & (BN / 8 - 1)) << 3);
                v[j] = T[row * S + cs];
            }
            int gcol = n0 + d;
            int hh2 = (gcol >> 6) & 7, dd2 = gcol & 63;
            int grow = m0 + nb8;
            int bb = grow >> 12, nn = grow & 4095;
            *(bf16x8*)&Vt[(size_t)(((bb * 8 + hh2) * 64 + dd2)) * LDKV + nn] = v;
        }
    }
}

// ---------------- K-feature GEMM (single pass; coalesced KPt via LDS transpose) ----------------
__global__ __launch_bounds__(256) void feat_kernel(const bf16_t* __restrict__ qkvb,
                                                   const bf16_t* __restrict__ projb,
                                                   bf16_t* __restrict__ outp,
                                                   float* __restrict__ ksum_part) {
    int bid = blockIdx.x;
    int bh = bid >> 5, tile = bid & 31;
    int b = bh >> 3, hh = bh & 7;
    int tid = threadIdx.x, wv = tid >> 6, ln = tid & 63;
    __shared__ __attribute__((aligned(16))) bf16_t AsBs[128 * 64 + 256 * 64];
    bf16_t* As = AsBs;
    bf16_t* Bs = AsBs + 128 * 64;
    __shared__ float diag_s[128];
    __shared__ float ksp_s[256];
    int n0 = tile * 128;
    int qoff = 512 + hh * 64;
    int lrow8 = ln >> 3;
    int lchunk = ((ln & 7) ^ (lrow8 & 7)) * 8;
#pragma unroll
    for (int i = 0; i < 4; i++) {
        int e = wv * 4 + i;
        size_t src = (size_t)(b * SEQN + n0 + e * 8 + lrow8) * LDQ + qoff + lchunk;
        __builtin_amdgcn_global_load_lds(AS1(qkvb + src), AS3(&As[e * 512]), 16, 0, 0);
    }
#pragma unroll
    for (int i = 0; i < 8; i++) {
        int e = wv * 8 + i;
        size_t src = (size_t)(e * 8 + lrow8) * 64 + lchunk;
        __builtin_amdgcn_global_load_lds(AS1(projb + src), AS3(&Bs[e * 512]), 16, 0, 0);
    }
    __syncthreads();
    if (tid < 128) {
        float s = 0.f;
#pragma unroll
        for (int c = 0; c < 8; c++) {
            bf16x8 v = *(const bf16x8*)&As[tid * 64 + ((c ^ (tid & 7)) * 8)];
#pragma unroll
            for (int j = 0; j < 8; j++) { float f = (float)v[j]; s += f * f; }
        }
        diag_s[tid] = s * (0.5f * DN * DN);
    }
    int wr = (wv >> 1) * 64, wc = (wv & 1) * 128;
    int lr = ln & 15, kg = ln >> 4, rq = kg * 4;
    f32x4v acc[4][8] = {};
#pragma unroll
    for (int ks = 0; ks < 2; ks++) {
        int g = ks * 4 + kg;
        bf16x8 af[4], bfv[8];
#pragma unroll
        for (int m = 0; m < 4; m++) {
            int row = wr + m * 16 + lr;
            af[m] = *(const bf16x8*)&As[row * 64 + ((g ^ (row & 7)) * 8)];
        }
#pragma unroll
        for (int n = 0; n < 8; n++) {
            int row = wc + n * 16 + lr;
            bfv[n] = *(const bf16x8*)&Bs[row * 64 + ((g ^ (row & 7)) * 8)];
        }
#pragma unroll
        for (int m = 0; m < 4; m++)
#pragma unroll
            for (int n = 0; n < 8; n++)
                acc[m][n] = __builtin_amdgcn_mfma_f32_16x16x32_bf16(af[m], bfv[n], acc[m][n], 0, 0, 0);
    }
    __syncthreads();
    float sj[8] = {};
#pragma unroll
    for (int m = 0; m < 4; m++) {
#pragma unroll
        for (int n = 0; n < 8; n++) {
#pragma unroll
            for (int r = 0; r < 4; r++) {
                int row = wr + m * 16 + rq + r;
                float val = RATIO * (__expf(acc[m][n][r] * DN - diag_s[row]) + EPSK);
                acc[m][n][r] = val;
                sj[n] += val;
            }
        }
    }
#pragma unroll
    for (int n = 0; n < 8; n++) {
        sj[n] += __shfl_xor(sj[n], 16);
        sj[n] += __shfl_xor(sj[n], 32);
    }
    if (wv < 2 && ln < 16) {
#pragma unroll
        for (int n = 0; n < 8; n++) ksp_s[wc + n * 16 + ln] = sj[n];
    }
    __syncthreads();
    if (wv >= 2 && ln < 16) {
#pragma unroll
        for (int n = 0; n < 8; n++) ksp_s[wc + n * 16 + ln] += sj[n];
    }
    __syncthreads();
    ksum_part[(size_t)bid * 256 + tid] = ksp_s[tid];
    bf16_t* T = AsBs;
#pragma unroll
    for (int hf = 0; hf < 2; hf++) {
        if ((wv & 1) == hf) {
#pragma unroll
            for (int n = 0; n < 8; n++) {
                int mm = n * 16 + lr;
#pragma unroll
                for (int m = 0; m < 4; m++) {
                    int nnb = wr + m * 16 + rq;
                    bf16x4 v;
#pragma unroll
                    for (int r = 0; r < 4; r++) v[r] = (bf16_t)acc[m][n][r];
                    *(bf16x4*)&T[mm * 136 + nnb] = v;
                }
            }
        }
        __syncthreads();
#pragma unroll
        for (int i = 0; i < 8; i++) {
            int u = i * 256 + tid;
            int mm = u >> 4, nc = u & 15;
            bf16x8 v = *(const bf16x8*)&T[mm * 136 + nc * 8];
            *(bf16x8*)&outp[(size_t)(bh * MF + hf * 128 + mm) * LDKV + n0 + nc * 8] = v;
        }
        __syncthreads();
    }
}

// ---------------- ctx split-K GEMM (KPt/Vt pitch LDKV) ----------------
__global__ __launch_bounds__(256) void ctx_gemm(const bf16_t* __restrict__ KPt,
                                                const bf16_t* __restrict__ Vt,
                                                float* __restrict__ part) {
    int bh = blockIdx.y;
    int mtile = blockIdx.x & 1, kc = blockIdx.x >> 1;
    int m0 = mtile * 128, nb = kc * 512;
    int tid = threadIdx.x, wv = tid >> 6, ln = tid & 63;
    __shared__ __attribute__((aligned(16))) bf16_t As[128 * 64];
    __shared__ __attribute__((aligned(16))) bf16_t Bs[64 * 64];
    int lrow8 = ln >> 3;
    int lchunk = ((ln & 7) ^ (lrow8 & 7)) * 8;
    int lr = ln & 15, kg = ln >> 4, rq = kg * 4;
    int wr = wv * 32;
    f32x4v acc[2][4] = {};
    for (int kt = 0; kt < 8; kt++) {
        int noff = nb + kt * 64;
        __syncthreads();
#pragma unroll
        for (int i = 0; i < 4; i++) {
            int e = wv * 4 + i;
            __builtin_amdgcn_global_load_lds(
                AS1(KPt + (size_t)(bh * MF + m0 + e * 8 + lrow8) * LDKV + noff + lchunk),
                AS3(&As[e * 512]), 16, 0, 0);
        }
#pragma unroll
        for (int i = 0; i < 2; i++) {
            int e = wv * 2 + i;
            __builtin_amdgcn_global_load_lds(
                AS1(Vt + (size_t)(bh * 64 + e * 8 + lrow8) * LDKV + noff + lchunk),
                AS3(&Bs[e * 512]), 16, 0, 0);
        }
        __syncthreads();
#pragma unroll
        for (int ks = 0; ks < 2; ks++) {
            int g = ks * 4 + kg;
            bf16x8 af[2], bfv[4];
#pragma unroll
            for (int m = 0; m < 2; m++) {
                int row = wr + m * 16 + lr;
                af[m] = *(const bf16x8*)&As[row * 64 + ((g ^ (row & 7)) * 8)];
            }
#pragma unroll
            for (int n = 0; n < 4; n++) {
                int row = n * 16 + lr;
                bfv[n] = *(const bf16x8*)&Bs[row * 64 + ((g ^ (row & 7)) * 8)];
            }
#pragma unroll
            for (int m = 0; m < 2; m++)
#pragma unroll
                for (int n = 0; n < 4; n++)
                    acc[m][n] = __builtin_amdgcn_mfma_f32_16x16x32_bf16(af[m], bfv[n], acc[m][n], 0, 0, 0);
        }
    }
#pragma unroll
    for (int m = 0; m < 2; m++)
#pragma unroll
        for (int n = 0; n < 4; n++)
#pragma unroll
            for (int r = 0; r < 4; r++)
                part[((size_t)(kc * 16 + bh) * MF + m0 + wr + m * 16 + rq + r) * 64 + n * 16 + lr] =
                    acc[m][n][r];
}

// ---------------- ctx reduce -> ctx_t[bh][d][m] bf16; + ksum reduce ----------------
__global__ __launch_bounds__(256) void ctx_reduce_kernel(const float* __restrict__ part,
                                                         const float* __restrict__ ksum_part,
                                                         bf16_t* __restrict__ ctx_t,
                                                         float* __restrict__ ksum) {
    int bh = blockIdx.x;
    for (int it = 0; it < 64; it++) {
        int idx = it * 256 + threadIdx.x;
        int m = idx >> 6, d = idx & 63;
        float s = 0.f;
#pragma unroll
        for (int kc = 0; kc < 8; kc++)
            s += part[(size_t)(kc * 16 + bh) * 16384 + idx];
        ctx_t[((size_t)bh * 64 + d) * MF + m] = (bf16_t)s;
    }
    {
        float s = 0.f;
#pragma unroll
        for (int t = 0; t < 32; t++)
            s += ksum_part[((size_t)bh * 32 + t) * 256 + threadIdx.x];
        ksum[bh * MF + threadIdx.x] = s;
    }
}

// ---------------- fused Q-side: q-features + dinv + (qp@ctx)*dinv -> abuf ----------------
__global__ __launch_bounds__(256) void qfused_kernel(const bf16_t* __restrict__ qkvb,
                                                     const bf16_t* __restrict__ projb,
                                                     const bf16_t* __restrict__ ctx_t,
                                                     const float* __restrict__ ksumb,
                                                     bf16_t* __restrict__ abuf) {
    int bid = blockIdx.x;
    int bh = bid >> 5, tile = bid & 31;
    int b = bh >> 3, hh = bh & 7;
    int tid = threadIdx.x, wv = tid >> 6, ln = tid & 63;
    __shared__ __attribute__((aligned(16))) bf16_t Qs[128 * 64];
    __shared__ __attribute__((aligned(16))) bf16_t Ps[256 * 64];
    __shared__ __attribute__((aligned(16))) bf16_t Cs[64 * 256];
    __shared__ float diag_s[128];
    __shared__ float dsum_s[128];
    int n0 = tile * 128;
    int lrow8 = ln >> 3;
    int lchunk = ((ln & 7) ^ (lrow8 & 7)) * 8;
#pragma unroll
    for (int i = 0; i < 4; i++) {
        int e = wv * 4 + i;
        size_t src = (size_t)(b * SEQN + n0 + e * 8 + lrow8) * LDQ + hh * 64 + lchunk;
        __builtin_amdgcn_global_load_lds(AS1(qkvb + src), AS3(&Qs[e * 512]), 16, 0, 0);
    }
#pragma unroll
    for (int i = 0; i < 8; i++) {
        int e = wv * 8 + i;
        size_t src = (size_t)(e * 8 + lrow8) * 64 + lchunk;
        __builtin_amdgcn_global_load_lds(AS1(projb + src), AS3(&Ps[e * 512]), 16, 0, 0);
    }
#pragma unroll
    for (int i = 0; i < 8; i++) {
        int c = i * 256 + tid;
        int cb = i * 256 + (tid & ~63);
        int crow = c >> 5, cch = c & 31;
        size_t src = ((size_t)bh * 64 + crow) * 256 + (size_t)(cch ^ (crow & 7)) * 8;
        __builtin_amdgcn_global_load_lds(AS1(ctx_t + src), AS3(Cs + (size_t)cb * 8), 16, 0, 0);
    }
    int wr = (wv >> 1) * 64, wc = (wv & 1) * 128;
    int lr = ln & 15, kg = ln >> 4, rq = kg * 4;
    float ksum_r[8];
#pragma unroll
    for (int n = 0; n < 8; n++) ksum_r[n] = ksumb[bh * MF + wc + n * 16 + lr];
    __syncthreads();
    if (tid < 128) {
        float s = 0.f;
#pragma unroll
        for (int c = 0; c < 8; c++) {
            bf16x8 v = *(const bf16x8*)&Qs[tid * 64 + ((c ^ (tid & 7)) * 8)];
#pragma unroll
            for (int j = 0; j < 8; j++) { float f = (float)v[j]; s += f * f; }
        }
        diag_s[tid] = s * (0.5f * DN * DN);
    }
    f32x4v acc[4][8] = {};
#pragma unroll
    for (int ks = 0; ks < 2; ks++) {
        int g = ks * 4 + kg;
        bf16x8 af[4], bfv[8];
#pragma unroll
        for (int m = 0; m < 4; m++) {
            int row = wr + m * 16 + lr;
            af[m] = *(const bf16x8*)&Qs[row * 64 + ((g ^ (row & 7)) * 8)];
        }
#pragma unroll
        for (int n = 0; n < 8; n++) {
            int row = wc + n * 16 + lr;
            bfv[n] = *(const bf16x8*)&Ps[row * 64 + ((g ^ (row & 7)) * 8)];
        }
#pragma unroll
        for (int m = 0; m < 4; m++)
#pragma unroll
            for (int n = 0; n < 8; n++)
                acc[m][n] = __builtin_amdgcn_mfma_f32_16x16x32_bf16(af[m], bfv[n], acc[m][n], 0, 0, 0);
    }
    __syncthreads();
    float dsum_p[4][4];
#pragma unroll
    for (int m = 0; m < 4; m++) {
#pragma unroll
        for (int r = 0; r < 4; r++) {
            int row = wr + m * 16 + rq + r;
            float dg = diag_s[row];
            float ds = 0.f;
#pragma unroll
            for (int n = 0; n < 8; n++) {
                float val = RATIO * (__expf(acc[m][n][r] * DN - dg) + EPSK);
                acc[m][n][r] = val;
                ds += val * ksum_r[n];
            }
            dsum_p[m][r] = ds;
        }
    }
#pragma unroll
    for (int m = 0; m < 4; m++)
#pragma unroll
        for (int r = 0; r < 4; r++) {
#pragma unroll
            for (int mask = 1; mask < 16; mask <<= 1)
                dsum_p[m][r] += __shfl_xor(dsum_p[m][r], mask);
        }
    if ((wv & 1) == 0 && lr == 0) {
#pragma unroll
        for (int m = 0; m < 4; m++)
#pragma unroll
            for (int r = 0; r < 4; r++)
                dsum_s[wr + m * 16 + rq + r] = dsum_p[m][r];
    }
    __syncthreads();
    if ((wv & 1) == 1 && lr == 0) {
#pragma unroll
        for (int m = 0; m < 4; m++)
#pragma unroll
            for (int r = 0; r < 4; r++) {
                int row = wr + m * 16 + rq + r;
                dsum_s[row] = 1.0f / (dsum_s[row] + dsum_p[m][r]);
            }
    }
    __syncthreads();
    f32x4v acc_o[4][2] = {};
#pragma unroll
    for (int h = 0; h < 2; h++) {
        if ((wv & 1) == h) {
#pragma unroll
            for (int m = 0; m < 4; m++)
#pragma unroll
                for (int n = 0; n < 8; n++)
#pragma unroll
                    for (int r = 0; r < 4; r++) {
                        int row = wr + m * 16 + rq + r;
                        int ml = n * 16 + lr;
                        Ps[row * 128 + (((ml >> 3) ^ (row & 7)) * 8) + (ml & 7)] =
                            (bf16_t)acc[m][n][r];
                    }
        }
        __syncthreads();
#pragma unroll
        for (int ku = 0; ku < 4; ku++) {
            int g = ku * 4 + kg;
            bf16x8 af[4], bfv[2];
#pragma unroll
            for (int m = 0; m < 4; m++) {
                int row = wr + m * 16 + lr;
                af[m] = *(const bf16x8*)&Ps[row * 128 + ((g ^ (row & 7)) * 8)];
            }
#pragma unroll
            for (int n = 0; n < 2; n++) {
                int rowd = (wv & 1) * 32 + n * 16 + lr;
                int ch = (h * 16 + g) ^ (rowd & 7);
                bfv[n] = *(const bf16x8*)&Cs[(rowd * 32 + ch) * 8];
            }
#pragma unroll
            for (int m = 0; m < 4; m++)
#pragma unroll
                for (int n = 0; n < 2; n++)
                    acc_o[m][n] = __builtin_amdgcn_mfma_f32_16x16x32_bf16(af[m], bfv[n], acc_o[m][n], 0, 0, 0);
        }
        __syncthreads();
    }
#pragma unroll
    for (int m = 0; m < 4; m++) {
#pragma unroll
        for (int r = 0; r < 4; r++) {
            int rowl = wr + m * 16 + rq + r;
            float di = dsum_s[rowl];
            size_t obase = (size_t)(b * SEQN + n0 + rowl) * LDY + hh * 64;
#pragma unroll
            for (int n = 0; n < 2; n++) {
                int d = (wv & 1) * 32 + n * 16 + lr;
                abuf[obase + d] = (bf16_t)(acc_o[m][n][r] * di);
            }
        }
    }
}

extern "C" void kernel_launch(void* const* d_in, const int* in_sizes, int n_in,
                              void* d_out, int out_size, void* d_ws, size_t ws_size,
                              hipStream_t stream) {
    const float* x     = (const float*)d_in[0];
    const float* proj  = (const float*)d_in[1];
    const float* ln1_g = (const float*)d_in[2];
    const float* ln1_b = (const float*)d_in[3];
    const float* Wqkv  = (const float*)d_in[4];
    const float* bqkv  = (const float*)d_in[5];
    const float* Wo    = (const float*)d_in[6];
    const float* bo    = (const float*)d_in[7];
    const float* ln2_g = (const float*)d_in[8];
    const float* ln2_b = (const float*)d_in[9];
    const float* Wff1  = (const float*)d_in[10];
    const float* bff1  = (const float*)d_in[11];
    const float* Wff2  = (const float*)d_in[12];
    const float* bff2  = (const float*)d_in[13];

    float* h = (float*)d_out;
    char* ws = (char*)d_ws;
    // Region A [0, 34,078,720): KPt (4096 rows x LDKV); aliases:
    bf16_t* KPt   = (bf16_t*)(ws);
    bf16_t* ybf   = (bf16_t*)(ws);               // [0, 8,912,896)
    bf16_t* pWo   = (bf16_t*)(ws + 8912896);     // [8,912,896, 17,301,504)
    bf16_t* pFF2  = (bf16_t*)(ws + 17301504);    // [17,301,504, 25,690,112)
    // Region B: qkvb (8192 x LDQ)
    bf16_t* qkvb  = (bf16_t*)(ws + 34078720);    // 17,301,504 B -> ends 51,380,224
    // Region C [51,380,224, 85,458,944): abuf/ctx_part/ksum_part; ffmid aliases whole C
    bf16_t* abufb = (bf16_t*)(ws + 51380224);    // 8,912,896
    float*  ctx_part  = (float*)(ws + 60293120); // 8,388,608
    float*  ksum_part = (float*)(ws + 68681728); // 524,288
    bf16_t* ffmidb    = (bf16_t*)(ws + 51380224);// 34,078,720 -> ends 85,458,944
    // Region D: Vt (1024 x LDKV)
    bf16_t* Vt    = (bf16_t*)(ws + 85458944);    // 8,519,680 -> ends 93,978,624
    bf16_t* projb = (bf16_t*)(ws + 93978624);    // 131,072
    bf16_t* ctx_t = (bf16_t*)(ws + 94109696);    // 524,288
    float*  ksumb = (float*)(ws + 94633984);     // 16,384
    bf16_t* wbase = (bf16_t*)(ws + 94650368);    // 4 slots x 6,815,744 B
    const size_t WSLOT = 3407872;
    bool hoist = ws_size >= (size_t)94650368 + 4 * 6815744;

    pconv_kernel<<<64, 256, 0, stream>>>(proj, projb);
    if (hoist)
        wconv_all<<<dim3(3072, 4), 256, 0, stream>>>(Wqkv, Wo, Wff1, Wff2, wbase);

    for (int i = 0; i < DEPTH; i++) {
        const bf16_t* pj = projb + (size_t)i * MF * DH;
        if (!hoist)
            wconv_all<<<dim3(3072, 1), 256, 0, stream>>>(
                Wqkv + (size_t)i * 786432, Wo + (size_t)i * 262144,
                Wff1 + (size_t)i * 1048576, Wff2 + (size_t)i * 1048576, wbase);
        bf16_t* wl = wbase + (hoist ? (size_t)i * WSLOT : 0);
        bf16_t* wq_t = wl;
        bf16_t* wo_t = wl + 835584;
        bf16_t* w1_t = wl + 1114112;
        bf16_t* w2_t = wl + 2228224;

        if (i == 0)
            ln_kernel<<<NROWS, 256, 0, stream>>>(x, ln1_g, ln1_b, ybf);
        else
            ln_add_kernel<<<NROWS, 256, 0, stream>>>(h, h, pFF2, ln1_g + i * DMODEL,
                                                     ln1_b + i * DMODEL, ybf);
        gemm_pipe<128, 64, 32, 3, 0, 0, 1>
            <<<dim3(1536 / 64, NROWS / 128), 256, 0, stream>>>(
            ybf, wq_t, bqkv + i * 1536, qkvb, Vt, 512, LDY, 544, LDQ);
        feat_kernel<<<512, 256, 0, stream>>>(qkvb, pj, KPt, ksum_part);
        ctx_gemm<<<dim3(16, 16), 256, 0, stream>>>(KPt, Vt, ctx_part);
        ctx_reduce_kernel<<<16, 256, 0, stream>>>(ctx_part, ksum_part, ctx_t, ksumb);
        qfused_kernel<<<512, 256, 0, stream>>>(qkvb, pj, ctx_t, ksumb, abufb);
        gemm_pipe<128, 64, 32, 3, 0, 1, 0>
            <<<dim3(512 / 64, NROWS / 128), 256, 0, stream>>>(
            abufb, wo_t, bo + i * DMODEL, pWo, nullptr, 512, LDY, 544, 512);

        ln_add_kernel<<<NROWS, 256, 0, stream>>>(i == 0 ? x : h, h, pWo,
                                                 ln2_g + i * DMODEL,
                                                 ln2_b + i * DMODEL, ybf);
        gemm_pipe<128, 64, 32, 3, 1, 1, 0>
            <<<dim3(2048 / 64, NROWS / 128), 256, 0, stream>>>(
            ybf, w1_t, bff1 + i * FFD, ffmidb, nullptr, 512, LDY, 544, LDF);
        gemm_pipe<128, 64, 32, 3, 0, 1, 0>
            <<<dim3(512 / 64, NROWS / 128), 256, 0, stream>>>(
            ffmidb, w2_t, bff2 + i * DMODEL, pFF2, nullptr, 2048, LDF, 2080, 512);
    }
    add_kernel<<<4096, 256, 0, stream>>>(h, pFF2);
}

// Round 20
// 717.276 us; speedup vs baseline: 1.1473x; 1.1473x over previous
//
#include <hip/hip_runtime.h>
#include <math.h>

#define DEPTH 4
#define DMODEL 512
#define DH 64
#define MF 256
#define FFD 2048
#define SEQN 4096
#define NROWS 8192

typedef __bf16 bf16_t;
typedef bf16_t bf16x8 __attribute__((ext_vector_type(8)));
typedef bf16_t bf16x4 __attribute__((ext_vector_type(4)));
typedef bf16_t bf16x2 __attribute__((ext_vector_type(2)));
typedef float f32x4v __attribute__((ext_vector_type(4)));

static constexpr float DN = 0.35355339059327373f;   // 64^-0.25
static constexpr float RATIO = 0.0625f;             // 256^-0.5
static constexpr float EPSK = 1e-4f;

__device__ __forceinline__ float gelu_fast(float x) {
    float z2 = x * (1.5957691216f + 0.0713548162f * x * x);
    return x / (1.0f + __expf(-z2));
}

#define AS1(p) ((const __attribute__((address_space(1))) void*)(p))
#define AS3(p) ((__attribute__((address_space(3))) void*)(p))

template <int N> __device__ __forceinline__ void wait_vmcnt() {
    if constexpr (N == 0) asm volatile("s_waitcnt vmcnt(0)" ::: "memory");
    else if constexpr (N == 1) asm volatile("s_waitcnt vmcnt(1)" ::: "memory");
    else if constexpr (N == 2) asm volatile("s_waitcnt vmcnt(2)" ::: "memory");
    else if constexpr (N == 3) asm volatile("s_waitcnt vmcnt(3)" ::: "memory");
    else if constexpr (N == 4) asm volatile("s_waitcnt vmcnt(4)" ::: "memory");
    else if constexpr (N == 5) asm volatile("s_waitcnt vmcnt(5)" ::: "memory");
    else if constexpr (N == 6) asm volatile("s_waitcnt vmcnt(6)" ::: "memory");
    else if constexpr (N == 8) asm volatile("s_waitcnt vmcnt(8)" ::: "memory");
    else asm volatile("s_waitcnt vmcnt(12)" ::: "memory");
}

// ---------------- LayerNorm -> bf16 (no residual; src may be x or h) ----------------
__global__ __launch_bounds__(256) void ln_kernel(const float* __restrict__ h,
                                                 const float* __restrict__ g,
                                                 const float* __restrict__ b,
                                                 bf16_t* __restrict__ y) {
    int row = blockIdx.x, tid = threadIdx.x;
    const float* hr = h + (size_t)row * DMODEL;
    float v0 = hr[tid], v1 = hr[tid + 256];
    __shared__ float s_sum[256], s_sq[256];
    s_sum[tid] = v0 + v1;
    s_sq[tid] = v0 * v0 + v1 * v1;
    __syncthreads();
    for (int off = 128; off > 0; off >>= 1) {
        if (tid < off) { s_sum[tid] += s_sum[tid + off]; s_sq[tid] += s_sq[tid + off]; }
        __syncthreads();
    }
    float mu = s_sum[0] * (1.0f / DMODEL);
    float var = s_sq[0] * (1.0f / DMODEL) - mu * mu;
    float rstd = rsqrtf(var + 1e-5f);
    bf16_t* yr = y + (size_t)row * DMODEL;
    yr[tid]       = (bf16_t)((v0 - mu) * rstd * g[tid] + b[tid]);
    yr[tid + 256] = (bf16_t)((v1 - mu) * rstd * g[tid + 256] + b[tid + 256]);
}

// ---------------- fused: hout = hin + P (bf16); LayerNorm -> bf16 ----------------
__global__ __launch_bounds__(256) void ln_add_kernel(const float* __restrict__ hin,
                                                     float* __restrict__ hout,
                                                     const bf16_t* __restrict__ p,
                                                     const float* __restrict__ g,
                                                     const float* __restrict__ b,
                                                     bf16_t* __restrict__ y) {
    int row = blockIdx.x, tid = threadIdx.x;
    const float* hr = hin + (size_t)row * DMODEL;
    const bf16_t* pr = p + (size_t)row * DMODEL;
    float2 hv = *(const float2*)(hr + 2 * tid);
    bf16x2 pv = *(const bf16x2*)(pr + 2 * tid);
    float v0 = hv.x + (float)pv[0];
    float v1 = hv.y + (float)pv[1];
    float2 outv; outv.x = v0; outv.y = v1;
    *(float2*)(hout + (size_t)row * DMODEL + 2 * tid) = outv;
    __shared__ float s_sum[256], s_sq[256];
    s_sum[tid] = v0 + v1;
    s_sq[tid] = v0 * v0 + v1 * v1;
    __syncthreads();
    for (int off = 128; off > 0; off >>= 1) {
        if (tid < off) { s_sum[tid] += s_sum[tid + off]; s_sq[tid] += s_sq[tid + off]; }
        __syncthreads();
    }
    float mu = s_sum[0] * (1.0f / DMODEL);
    float var = s_sq[0] * (1.0f / DMODEL) - mu * mu;
    float rstd = rsqrtf(var + 1e-5f);
    bf16x2 ov;
    ov[0] = (bf16_t)((v0 - mu) * rstd * g[2 * tid] + b[2 * tid]);
    ov[1] = (bf16_t)((v1 - mu) * rstd * g[2 * tid + 1] + b[2 * tid + 1]);
    *(bf16x2*)(y + (size_t)row * DMODEL + 2 * tid) = ov;
}

// ---------------- tail: h += P (bf16) ----------------
__global__ __launch_bounds__(256) void add_kernel(float* __restrict__ h,
                                                  const bf16_t* __restrict__ p) {
    size_t i = ((size_t)blockIdx.x * 256 + threadIdx.x) * 4;
    float4 hv = *(const float4*)(h + i);
    bf16x4 pv = *(const bf16x4*)(p + i);
    hv.x += (float)pv[0]; hv.y += (float)pv[1];
    hv.z += (float)pv[2]; hv.w += (float)pv[3];
    *(float4*)(h + i) = hv;
}

// ---------------- weight transpose+convert; blockIdx.y = layer offset ----------------
__global__ __launch_bounds__(256) void wconv_all(const float* __restrict__ Wqkv,
                                                 const float* __restrict__ Wo,
                                                 const float* __restrict__ Wff1,
                                                 const float* __restrict__ Wff2,
                                                 bf16_t* __restrict__ wslot) {
    __shared__ float t[32][33];
    int layer = blockIdx.y;
    int bid = blockIdx.x;
    const float* W; bf16_t* Wt; int K, N, nx, lb;
    bf16_t* slot = wslot + (size_t)layer * 3407872;
    if (bid < 768)       { W = Wqkv + (size_t)layer * 786432;  Wt = slot;           K = 512;  N = 1536; nx = 48; lb = bid; }
    else if (bid < 1024) { W = Wo   + (size_t)layer * 262144;  Wt = slot + 786432;  K = 512;  N = 512;  nx = 16; lb = bid - 768; }
    else if (bid < 2048) { W = Wff1 + (size_t)layer * 1048576; Wt = slot + 1048576; K = 512;  N = 2048; nx = 64; lb = bid - 1024; }
    else                 { W = Wff2 + (size_t)layer * 1048576; Wt = slot + 2097152; K = 2048; N = 512;  nx = 16; lb = bid - 2048; }
    int n0 = (lb % nx) * 32, k0 = (lb / nx) * 32;
    int tx = threadIdx.x & 31, ty = threadIdx.x >> 5;
#pragma unroll
    for (int i = 0; i < 32; i += 8)
        t[ty + i][tx] = W[(size_t)(k0 + ty + i) * N + n0 + tx];
    __syncthreads();
#pragma unroll
    for (int i = 0; i < 32; i += 8)
        Wt[(size_t)(n0 + ty + i) * K + k0 + tx] = (bf16_t)t[tx][ty + i];
}

// ---------------- proj -> bf16 ----------------
__global__ __launch_bounds__(256) void pconv_kernel(const float* __restrict__ proj,
                                                    bf16_t* __restrict__ projb) {
    int i = (blockIdx.x * 256 + threadIdx.x) * 4;
    float4 v = *(const float4*)(proj + i);
    bf16x4 o;
    o[0] = (bf16_t)v.x; o[1] = (bf16_t)v.y; o[2] = (bf16_t)v.z; o[3] = (bf16_t)v.w;
    *(bf16x4*)(projb + i) = o;
}

// ---------------- 128x64 BK=32 P=3 pipelined MFMA GEMM, hoisted addressing ----------------
template <int BM, int BN, int BK, int P, int ACT, int RES, int WF, int WB, int QKVE>
__global__ __launch_bounds__(256) void gemm_pipe(const bf16_t* __restrict__ A,
                                                 const bf16_t* __restrict__ Bt,
                                                 const float* __restrict__ bias,
                                                 float* __restrict__ Cf,
                                                 bf16_t* __restrict__ Cb,
                                                 bf16_t* __restrict__ Vt,
                                                 int N, int K) {
    static_assert(BK == 32, "BK fixed at 32 (KS==1)");
    constexpr int MR = BM / 2 / 16;
    constexpr int NR = BN / 2 / 16;
    constexpr int CH = BK / 8;
    constexpr int SWZ = CH - 1;
    constexpr int TILE = (BM + BN) * BK;
    constexpr int L = TILE / 8 / 256;
    __shared__ __attribute__((aligned(16))) bf16_t smem[P * TILE];
    int tid = threadIdx.x;
    int wv = tid >> 6, ln = tid & 63;
    int gx = gridDim.x;
    int lin = blockIdx.y * gx + blockIdx.x;
    int per = (gx * gridDim.y) >> 3;
    int orig = (lin & 7) * per + (lin >> 3);
    int m0 = (orig / gx) * BM, n0 = (orig % gx) * BN;
    int wr = (wv >> 1) * (MR * 16), wc = (wv & 1) * (NR * 16);
    int lr = ln & 15, kq8 = ln >> 4;
    int nsteps = K / BK;

    const bf16_t* gsrc[L];
    int ldst[L];
#pragma unroll
    for (int i = 0; i < L; i++) {
        int c = i * 256 + tid;
        int cb = i * 256 + (tid & ~63);
        bool inA = (c < BM * CH);
        int cc = inA ? c : c - BM * CH;
        int row = cc / CH, ch = cc % CH;
        const bf16_t* mat = inA ? A : Bt;
        int r0 = inA ? m0 : n0;
        int chs = ch ^ ((row ^ (row >> 2)) & SWZ);
        gsrc[i] = mat + (size_t)(r0 + row) * K + chs * 8;
        ldst[i] = cb * 8;
    }
    auto stage = [&](int tile, int sb) {
        int k0 = tile * BK;
        bf16_t* dst = smem + sb * TILE;
#pragma unroll
        for (int i = 0; i < L; i++)
            __builtin_amdgcn_global_load_lds(AS1(gsrc[i] + k0), AS3(dst + ldst[i]), 16, 0, 0);
    };

    int aoff[MR], boff[NR];
#pragma unroll
    for (int m = 0; m < MR; m++) {
        int row = wr + m * 16 + lr;
        aoff[m] = (row * CH + (kq8 ^ ((row ^ (row >> 2)) & SWZ))) * 8;
    }
#pragma unroll
    for (int n = 0; n < NR; n++) {
        int row = wc + n * 16 + lr;
        boff[n] = BM * BK + (row * CH + (kq8 ^ ((row ^ (row >> 2)) & SWZ))) * 8;
    }

    f32x4v acc[MR][NR] = {};
#pragma unroll
    for (int p = 0; p < P - 1; ++p) stage(p, p);

    int cur = 0;
    for (int t = 0; t < nsteps; ++t) {
        int rem = nsteps - 1 - t;
        if (rem >= P - 2) wait_vmcnt<(P - 2) * L>();
        else if constexpr (P >= 4) {
            if (rem == 1) wait_vmcnt<L>(); else wait_vmcnt<0>();
        } else wait_vmcnt<0>();
        __builtin_amdgcn_s_barrier();
        asm volatile("" ::: "memory");
        if (t + P - 1 < nsteps) {
            int sb = cur - 1; if (sb < 0) sb = P - 1;
            stage(t + P - 1, sb);
        }
        const bf16_t* base = smem + cur * TILE;
        bf16x8 af[MR], bfr[NR];
#pragma unroll
        for (int m = 0; m < MR; m++) af[m] = *(const bf16x8*)&base[aoff[m]];
#pragma unroll
        for (int n = 0; n < NR; n++) bfr[n] = *(const bf16x8*)&base[boff[n]];
        __builtin_amdgcn_s_setprio(1);
#pragma unroll
        for (int m = 0; m < MR; m++)
#pragma unroll
            for (int n = 0; n < NR; n++)
                acc[m][n] = __builtin_amdgcn_mfma_f32_16x16x32_bf16(af[m], bfr[n], acc[m][n], 0, 0, 0);
        __builtin_amdgcn_s_setprio(0);
        cur = (cur + 1 == P) ? 0 : cur + 1;
    }
    int rq = (ln >> 4) * 4;
    if (WB || QKVE) {
        __syncthreads();
        bf16_t* T = smem;
        constexpr int S = BN + 8;
#pragma unroll
        for (int n = 0; n < NR; n++) {
            int col = wc + n * 16 + lr;
            float bcol = bias[n0 + col];
#pragma unroll
            for (int m = 0; m < MR; m++) {
#pragma unroll
                for (int r = 0; r < 4; r++) {
                    int row = wr + m * 16 + rq + r;
                    float v = acc[m][n][r] + bcol;
                    if (ACT == 1) v = gelu_fast(v);
                    int cs = (col & 7) | ((((col >> 3) ^ (row >> 3)) & (BN / 8 - 1)) << 3);
                    T[row * S + cs] = (bf16_t)v;
                }
            }
        }
        __syncthreads();
        if (!QKVE || n0 < 1024) {
            int ldc = QKVE ? 1024 : N;
#pragma unroll
            for (int i = 0; i < BM * BN / 8 / 256; i++) {
                int e = i * 2048 + tid * 8;
                int row = e / BN, c0 = e % BN;
                int ch = ((c0 >> 3) ^ (row >> 3)) & (BN / 8 - 1);
                bf16x8 v = *(const bf16x8*)&T[row * S + ch * 8];
                *(bf16x8*)&Cb[(size_t)(m0 + row) * ldc + n0 + c0] = v;
            }
        } else {
#pragma unroll
            for (int i = 0; i < BM * BN / 8 / 256; i++) {
                int u = i * 256 + tid;
                int d = u & (BN - 1), nb8 = (u / BN) * 8;
                bf16x8 v;
#pragma unroll
                for (int j = 0; j < 8; j++) {
                    int row = nb8 + j;
                    int cs = (d & 7) | ((((d >> 3) ^ (row >> 3)) & (BN / 8 - 1)) << 3);
                    v[j] = T[row * S + cs];
                }
                int gcol = n0 + d;
                int hh2 = (gcol >> 6) & 7, dd2 = gcol & 63;
                int grow = m0 + nb8;
                int bb = grow >> 12, nn = grow & 4095;
                *(bf16x8*)&Vt[(((size_t)bb * 8 + hh2) * 64 + dd2) * 4096 + nn] = v;
            }
        }
    } else {
#pragma unroll
        for (int n = 0; n < NR; n++) {
            int col = n0 + wc + n * 16 + lr;
            float bcol = bias[col];
#pragma unroll
            for (int m = 0; m < MR; m++) {
#pragma unroll
                for (int r = 0; r < 4; r++) {
                    int row = m0 + wr + m * 16 + rq + r;
                    float v = acc[m][n][r] + bcol;
                    if (ACT == 1) v = gelu_fast(v);
                    size_t idx = (size_t)row * N + col;
                    if (RES) Cf[idx] += v;
                    else Cf[idx] = v;
                }
            }
        }
    }
}

// ---------------- K-feature GEMM (single pass; coalesced KPt via LDS transpose) ----------------
__global__ __launch_bounds__(256) void feat_kernel(const bf16_t* __restrict__ qkvb,
                                                   const bf16_t* __restrict__ projb,
                                                   bf16_t* __restrict__ outp,
                                                   float* __restrict__ ksum_part) {
    int bid = blockIdx.x;
    int bh = bid >> 5, tile = bid & 31;
    int b = bh >> 3, hh = bh & 7;
    int tid = threadIdx.x, wv = tid >> 6, ln = tid & 63;
    __shared__ __attribute__((aligned(16))) bf16_t AsBs[128 * 64 + 256 * 64];
    bf16_t* As = AsBs;
    bf16_t* Bs = AsBs + 128 * 64;
    __shared__ float diag_s[128];
    __shared__ float ksp_s[256];
    int n0 = tile * 128;
    int qoff = 512 + hh * 64;
    int lrow8 = ln >> 3;
    int lchunk = ((ln & 7) ^ (lrow8 & 7)) * 8;
#pragma unroll
    for (int i = 0; i < 4; i++) {
        int e = wv * 4 + i;
        size_t src = (size_t)(b * SEQN + n0 + e * 8 + lrow8) * 1024 + qoff + lchunk;
        __builtin_amdgcn_global_load_lds(AS1(qkvb + src), AS3(&As[e * 512]), 16, 0, 0);
    }
#pragma unroll
    for (int i = 0; i < 8; i++) {
        int e = wv * 8 + i;
        size_t src = (size_t)(e * 8 + lrow8) * 64 + lchunk;
        __builtin_amdgcn_global_load_lds(AS1(projb + src), AS3(&Bs[e * 512]), 16, 0, 0);
    }
    __syncthreads();
    if (tid < 128) {
        float s = 0.f;
#pragma unroll
        for (int c = 0; c < 8; c++) {
            bf16x8 v = *(const bf16x8*)&As[tid * 64 + ((c ^ (tid & 7)) * 8)];
#pragma unroll
            for (int j = 0; j < 8; j++) { float f = (float)v[j]; s += f * f; }
        }
        diag_s[tid] = s * (0.5f * DN * DN);
    }
    int wr = (wv >> 1) * 64, wc = (wv & 1) * 128;
    int lr = ln & 15, kg = ln >> 4, rq = kg * 4;
    f32x4v acc[4][8] = {};
#pragma unroll
    for (int ks = 0; ks < 2; ks++) {
        int g = ks * 4 + kg;
        bf16x8 af[4], bfv[8];
#pragma unroll
        for (int m = 0; m < 4; m++) {
            int row = wr + m * 16 + lr;
            af[m] = *(const bf16x8*)&As[row * 64 + ((g ^ (row & 7)) * 8)];
        }
#pragma unroll
        for (int n = 0; n < 8; n++) {
            int row = wc + n * 16 + lr;
            bfv[n] = *(const bf16x8*)&Bs[row * 64 + ((g ^ (row & 7)) * 8)];
        }
#pragma unroll
        for (int m = 0; m < 4; m++)
#pragma unroll
            for (int n = 0; n < 8; n++)
                acc[m][n] = __builtin_amdgcn_mfma_f32_16x16x32_bf16(af[m], bfv[n], acc[m][n], 0, 0, 0);
    }
    __syncthreads();
    float sj[8] = {};
#pragma unroll
    for (int m = 0; m < 4; m++) {
#pragma unroll
        for (int n = 0; n < 8; n++) {
#pragma unroll
            for (int r = 0; r < 4; r++) {
                int row = wr + m * 16 + rq + r;
                float val = RATIO * (__expf(acc[m][n][r] * DN - diag_s[row]) + EPSK);
                acc[m][n][r] = val;
                sj[n] += val;
            }
        }
    }
#pragma unroll
    for (int n = 0; n < 8; n++) {
        sj[n] += __shfl_xor(sj[n], 16);
        sj[n] += __shfl_xor(sj[n], 32);
    }
    if (wv < 2 && ln < 16) {
#pragma unroll
        for (int n = 0; n < 8; n++) ksp_s[wc + n * 16 + ln] = sj[n];
    }
    __syncthreads();
    if (wv >= 2 && ln < 16) {
#pragma unroll
        for (int n = 0; n < 8; n++) ksp_s[wc + n * 16 + ln] += sj[n];
    }
    __syncthreads();
    ksum_part[(size_t)bid * 256 + tid] = ksp_s[tid];
    bf16_t* T = AsBs;
#pragma unroll
    for (int hf = 0; hf < 2; hf++) {
        if ((wv & 1) == hf) {
#pragma unroll
            for (int n = 0; n < 8; n++) {
                int mm = n * 16 + lr;
#pragma unroll
                for (int m = 0; m < 4; m++) {
                    int nnb = wr + m * 16 + rq;
                    bf16x4 v;
#pragma unroll
                    for (int r = 0; r < 4; r++) v[r] = (bf16_t)acc[m][n][r];
                    *(bf16x4*)&T[mm * 136 + nnb] = v;
                }
            }
        }
        __syncthreads();
#pragma unroll
        for (int i = 0; i < 8; i++) {
            int u = i * 256 + tid;
            int mm = u >> 4, nc = u & 15;
            bf16x8 v = *(const bf16x8*)&T[mm * 136 + nc * 8];
            *(bf16x8*)&outp[((size_t)bh * MF + hf * 128 + mm) * 4096 + n0 + nc * 8] = v;
        }
        __syncthreads();
    }
}

// ---------------- ctx split-K GEMM ----------------
__global__ __launch_bounds__(256) void ctx_gemm(const bf16_t* __restrict__ KPt,
                                                const bf16_t* __restrict__ Vt,
                                                float* __restrict__ part) {
    int bh = blockIdx.y;
    int mtile = blockIdx.x & 1, kc = blockIdx.x >> 1;
    int m0 = mtile * 128, nb = kc * 512;
    int tid = threadIdx.x, wv = tid >> 6, ln = tid & 63;
    __shared__ __attribute__((aligned(16))) bf16_t As[128 * 64];
    __shared__ __attribute__((aligned(16))) bf16_t Bs[64 * 64];
    int lrow8 = ln >> 3;
    int lchunk = ((ln & 7) ^ (lrow8 & 7)) * 8;
    int lr = ln & 15, kg = ln >> 4, rq = kg * 4;
    int wr = wv * 32;
    f32x4v acc[2][4] = {};
    for (int kt = 0; kt < 8; kt++) {
        int noff = nb + kt * 64;
        __syncthreads();
#pragma unroll
        for (int i = 0; i < 4; i++) {
            int e = wv * 4 + i;
            __builtin_amdgcn_global_load_lds(
                AS1(KPt + ((size_t)bh * MF + m0 + e * 8 + lrow8) * 4096 + noff + lchunk),
                AS3(&As[e * 512]), 16, 0, 0);
        }
#pragma unroll
        for (int i = 0; i < 2; i++) {
            int e = wv * 2 + i;
            __builtin_amdgcn_global_load_lds(
                AS1(Vt + ((size_t)bh * 64 + e * 8 + lrow8) * 4096 + noff + lchunk),
                AS3(&Bs[e * 512]), 16, 0, 0);
        }
        __syncthreads();
#pragma unroll
        for (int ks = 0; ks < 2; ks++) {
            int g = ks * 4 + kg;
            bf16x8 af[2], bfv[4];
#pragma unroll
            for (int m = 0; m < 2; m++) {
                int row = wr + m * 16 + lr;
                af[m] = *(const bf16x8*)&As[row * 64 + ((g ^ (row & 7)) * 8)];
            }
#pragma unroll
            for (int n = 0; n < 4; n++) {
                int row = n * 16 + lr;
                bfv[n] = *(const bf16x8*)&Bs[row * 64 + ((g ^ (row & 7)) * 8)];
            }
#pragma unroll
            for (int m = 0; m < 2; m++)
#pragma unroll
                for (int n = 0; n < 4; n++)
                    acc[m][n] = __builtin_amdgcn_mfma_f32_16x16x32_bf16(af[m], bfv[n], acc[m][n], 0, 0, 0);
        }
    }
#pragma unroll
    for (int m = 0; m < 2; m++)
#pragma unroll
        for (int n = 0; n < 4; n++)
#pragma unroll
            for (int r = 0; r < 4; r++)
                part[((size_t)(kc * 16 + bh) * MF + m0 + wr + m * 16 + rq + r) * 64 + n * 16 + lr] =
                    acc[m][n][r];
}

// ---------------- ctx reduce (widened): grid = 16 bh x 16 chunks ----------------
__global__ __launch_bounds__(256) void ctx_reduce_kernel(const float* __restrict__ part,
                                                         const float* __restrict__ ksum_part,
                                                         bf16_t* __restrict__ ctx_t,
                                                         float* __restrict__ ksum) {
    int bh = blockIdx.x >> 4;
    int chunk = blockIdx.x & 15;
    for (int it = 0; it < 4; it++) {
        int idx = (chunk * 4 + it) * 256 + threadIdx.x;
        int m = idx >> 6, d = idx & 63;
        float s = 0.f;
#pragma unroll
        for (int kc = 0; kc < 8; kc++)
            s += part[(size_t)(kc * 16 + bh) * 16384 + idx];
        ctx_t[((size_t)bh * 64 + d) * MF + m] = (bf16_t)s;
    }
    if (chunk == 0) {
        float s = 0.f;
#pragma unroll
        for (int t = 0; t < 32; t++)
            s += ksum_part[((size_t)bh * 32 + t) * 256 + threadIdx.x];
        ksum[bh * MF + threadIdx.x] = s;
    }
}

// ---------------- fused Q-side: q-features + dinv + (qp@ctx)*dinv -> abuf ----------------
__global__ __launch_bounds__(256) void qfused_kernel(const bf16_t* __restrict__ qkvb,
                                                     const bf16_t* __restrict__ projb,
                                                     const bf16_t* __restrict__ ctx_t,
                                                     const float* __restrict__ ksumb,
                                                     bf16_t* __restrict__ abuf) {
    int bid = blockIdx.x;
    int bh = bid >> 5, tile = bid & 31;
    int b = bh >> 3, hh = bh & 7;
    int tid = threadIdx.x, wv = tid >> 6, ln = tid & 63;
    __shared__ __attribute__((aligned(16))) bf16_t Qs[128 * 64];
    __shared__ __attribute__((aligned(16))) bf16_t Ps[256 * 64];
    __shared__ __attribute__((aligned(16))) bf16_t Cs[64 * 256];
    __shared__ float diag_s[128];
    __shared__ float dsum_s[128];
    int n0 = tile * 128;
    int lrow8 = ln >> 3;
    int lchunk = ((ln & 7) ^ (lrow8 & 7)) * 8;
#pragma unroll
    for (int i = 0; i < 4; i++) {
        int e = wv * 4 + i;
        size_t src = (size_t)(b * SEQN + n0 + e * 8 + lrow8) * 1024 + hh * 64 + lchunk;
        __builtin_amdgcn_global_load_lds(AS1(qkvb + src), AS3(&Qs[e * 512]), 16, 0, 0);
    }
#pragma unroll
    for (int i = 0; i < 8; i++) {
        int e = wv * 8 + i;
        size_t src = (size_t)(e * 8 + lrow8) * 64 + lchunk;
        __builtin_amdgcn_global_load_lds(AS1(projb + src), AS3(&Ps[e * 512]), 16, 0, 0);
    }
#pragma unroll
    for (int i = 0; i < 8; i++) {
        int c = i * 256 + tid;
        int cb = i * 256 + (tid & ~63);
        int crow = c >> 5, cch = c & 31;
        size_t src = ((size_t)bh * 64 + crow) * 256 + (size_t)(cch ^ (crow & 7)) * 8;
        __builtin_amdgcn_global_load_lds(AS1(ctx_t + src), AS3(Cs + (size_t)cb * 8), 16, 0, 0);
    }
    int wr = (wv >> 1) * 64, wc = (wv & 1) * 128;
    int lr = ln & 15, kg = ln >> 4, rq = kg * 4;
    float ksum_r[8];
#pragma unroll
    for (int n = 0; n < 8; n++) ksum_r[n] = ksumb[bh * MF + wc + n * 16 + lr];
    __syncthreads();
    if (tid < 128) {
        float s = 0.f;
#pragma unroll
        for (int c = 0; c < 8; c++) {
            bf16x8 v = *(const bf16x8*)&Qs[tid * 64 + ((c ^ (tid & 7)) * 8)];
#pragma unroll
            for (int j = 0; j < 8; j++) { float f = (float)v[j]; s += f * f; }
        }
        diag_s[tid] = s * (0.5f * DN * DN);
    }
    f32x4v acc[4][8] = {};
#pragma unroll
    for (int ks = 0; ks < 2; ks++) {
        int g = ks * 4 + kg;
        bf16x8 af[4], bfv[8];
#pragma unroll
        for (int m = 0; m < 4; m++) {
            int row = wr + m * 16 + lr;
            af[m] = *(const bf16x8*)&Qs[row * 64 + ((g ^ (row & 7)) * 8)];
        }
#pragma unroll
        for (int n = 0; n < 8; n++) {
            int row = wc + n * 16 + lr;
            bfv[n] = *(const bf16x8*)&Ps[row * 64 + ((g ^ (row & 7)) * 8)];
        }
#pragma unroll
        for (int m = 0; m < 4; m++)
#pragma unroll
            for (int n = 0; n < 8; n++)
                acc[m][n] = __builtin_amdgcn_mfma_f32_16x16x32_bf16(af[m], bfv[n], acc[m][n], 0, 0, 0);
    }
    __syncthreads();
    float dsum_p[4][4];
#pragma unroll
    for (int m = 0; m < 4; m++) {
#pragma unroll
        for (int r = 0; r < 4; r++) {
            int row = wr + m * 16 + rq + r;
            float dg = diag_s[row];
            float ds = 0.f;
#pragma unroll
            for (int n = 0; n < 8; n++) {
                float val = RATIO * (__expf(acc[m][n][r] * DN - dg) + EPSK);
                acc[m][n][r] = val;
                ds += val * ksum_r[n];
            }
            dsum_p[m][r] = ds;
        }
    }
#pragma unroll
    for (int m = 0; m < 4; m++)
#pragma unroll
        for (int r = 0; r < 4; r++) {
#pragma unroll
            for (int mask = 1; mask < 16; mask <<= 1)
                dsum_p[m][r] += __shfl_xor(dsum_p[m][r], mask);
        }
    if ((wv & 1) == 0 && lr == 0) {
#pragma unroll
        for (int m = 0; m < 4; m++)
#pragma unroll
            for (int r = 0; r < 4; r++)
                dsum_s[wr + m * 16 + rq + r] = dsum_p[m][r];
    }
    __syncthreads();
    if ((wv & 1) == 1 && lr == 0) {
#pragma unroll
        for (int m = 0; m < 4; m++)
#pragma unroll
            for (int r = 0; r < 4; r++) {
                int row = wr + m * 16 + rq + r;
                dsum_s[row] = 1.0f / (dsum_s[row] + dsum_p[m][r]);
            }
    }
    __syncthreads();
    f32x4v acc_o[4][2] = {};
#pragma unroll
    for (int h = 0; h < 2; h++) {
        if ((wv & 1) == h) {
#pragma unroll
            for (int m = 0; m < 4; m++)
#pragma unroll
                for (int n = 0; n < 8; n++)
#pragma unroll
                    for (int r = 0; r < 4; r++) {
                        int row = wr + m * 16 + rq + r;
                        int ml = n * 16 + lr;
                        Ps[row * 128 + (((ml >> 3) ^ (row & 7)) * 8) + (ml & 7)] =
                            (bf16_t)acc[m][n][r];
                    }
        }
        __syncthreads();
#pragma unroll
        for (int ku = 0; ku < 4; ku++) {
            int g = ku * 4 + kg;
            bf16x8 af[4], bfv[2];
#pragma unroll
            for (int m = 0; m < 4; m++) {
                int row = wr + m * 16 + lr;
                af[m] = *(const bf16x8*)&Ps[row * 128 + ((g ^ (row & 7)) * 8)];
            }
#pragma unroll
            for (int n = 0; n < 2; n++) {
                int rowd = (wv & 1) * 32 + n * 16 + lr;
                int ch = (h * 16 + g) ^ (rowd & 7);
                bfv[n] = *(const bf16x8*)&Cs[(rowd * 32 + ch) * 8];
            }
#pragma unroll
            for (int m = 0; m < 4; m++)
#pragma unroll
                for (int n = 0; n < 2; n++)
                    acc_o[m][n] = __builtin_amdgcn_mfma_f32_16x16x32_bf16(af[m], bfv[n], acc_o[m][n], 0, 0, 0);
        }
        __syncthreads();
    }
#pragma unroll
    for (int m = 0; m < 4; m++) {
#pragma unroll
        for (int r = 0; r < 4; r++) {
            int rowl = wr + m * 16 + rq + r;
            float di = dsum_s[rowl];
            size_t obase = ((size_t)(b * SEQN + n0 + rowl)) * DMODEL + hh * 64;
#pragma unroll
            for (int n = 0; n < 2; n++) {
                int d = (wv & 1) * 32 + n * 16 + lr;
                abuf[obase + d] = (bf16_t)(acc_o[m][n][r] * di);
            }
        }
    }
}

extern "C" void kernel_launch(void* const* d_in, const int* in_sizes, int n_in,
                              void* d_out, int out_size, void* d_ws, size_t ws_size,
                              hipStream_t stream) {
    const float* x     = (const float*)d_in[0];
    const float* proj  = (const float*)d_in[1];
    const float* ln1_g = (const float*)d_in[2];
    const float* ln1_b = (const float*)d_in[3];
    const float* Wqkv  = (const float*)d_in[4];
    const float* bqkv  = (const float*)d_in[5];
    const float* Wo    = (const float*)d_in[6];
    const float* bo    = (const float*)d_in[7];
    const float* ln2_g = (const float*)d_in[8];
    const float* ln2_b = (const float*)d_in[9];
    const float* Wff1  = (const float*)d_in[10];
    const float* bff1  = (const float*)d_in[11];
    const float* Wff2  = (const float*)d_in[12];
    const float* bff2  = (const float*)d_in[13];

    float* h = (float*)d_out;
    char* ws = (char*)d_ws;
    bf16_t* KPt   = (bf16_t*)(ws);
    bf16_t* ybf   = (bf16_t*)(ws);               // [0, 8Mi)   (dead when KPt live)
    bf16_t* pWo   = (bf16_t*)(ws + 8388608);     // [8Mi,16Mi)
    bf16_t* pFF2  = (bf16_t*)(ws + 16777216);    // [16Mi,24Mi)
    bf16_t* qkvb  = (bf16_t*)(ws + 33554432);
    bf16_t* abufb = (bf16_t*)(ws + 50331648);
    float*  ctx_part  = (float*)(ws + 58720256);
    float*  ksum_part = (float*)(ws + 67108864);
    bf16_t* ffmidb    = (bf16_t*)(ws + 50331648);
    bf16_t* Vt    = (bf16_t*)(ws + 83886080);
    bf16_t* projb = (bf16_t*)(ws + 92274688);
    bf16_t* ctx_t = (bf16_t*)(ws + 92405760);
    float*  ksumb = (float*)(ws + 92930048);
    bf16_t* wbase = (bf16_t*)(ws + 93061120);
    const size_t WSLOT = 3407872;
    bool hoist = ws_size >= (size_t)93061120 + 4 * 6815744;

    pconv_kernel<<<64, 256, 0, stream>>>(proj, projb);
    if (hoist)
        wconv_all<<<dim3(3072, 4), 256, 0, stream>>>(Wqkv, Wo, Wff1, Wff2, wbase);

    for (int i = 0; i < DEPTH; i++) {
        const bf16_t* pj = projb + (size_t)i * MF * DH;
        if (!hoist)
            wconv_all<<<dim3(3072, 1), 256, 0, stream>>>(
                Wqkv + (size_t)i * 786432, Wo + (size_t)i * 262144,
                Wff1 + (size_t)i * 1048576, Wff2 + (size_t)i * 1048576, wbase);
        bf16_t* wl = wbase + (hoist ? (size_t)i * WSLOT : 0);
        bf16_t* wq_t = wl;
        bf16_t* wo_t = wl + 786432;
        bf16_t* w1_t = wl + 1048576;
        bf16_t* w2_t = wl + 2097152;

        if (i == 0)
            ln_kernel<<<NROWS, 256, 0, stream>>>(x, ln1_g, ln1_b, ybf);
        else
            ln_add_kernel<<<NROWS, 256, 0, stream>>>(h, h, pFF2, ln1_g + i * DMODEL,
                                                     ln1_b + i * DMODEL, ybf);
        gemm_pipe<128, 64, 32, 3, 0, 0, 0, 0, 1>
            <<<dim3(1536 / 64, NROWS / 128), 256, 0, stream>>>(
            ybf, wq_t, bqkv + i * 1536, nullptr, qkvb, Vt, 1536, 512);
        feat_kernel<<<512, 256, 0, stream>>>(qkvb, pj, KPt, ksum_part);
        ctx_gemm<<<dim3(16, 16), 256, 0, stream>>>(KPt, Vt, ctx_part);
        ctx_reduce_kernel<<<256, 256, 0, stream>>>(ctx_part, ksum_part, ctx_t, ksumb);
        qfused_kernel<<<512, 256, 0, stream>>>(qkvb, pj, ctx_t, ksumb, abufb);
        gemm_pipe<128, 64, 32, 3, 0, 0, 0, 1, 0>
            <<<dim3(512 / 64, NROWS / 128), 256, 0, stream>>>(
            abufb, wo_t, bo + i * DMODEL, nullptr, pWo, nullptr, 512, 512);

        ln_add_kernel<<<NROWS, 256, 0, stream>>>(i == 0 ? x : h, h, pWo,
                                                 ln2_g + i * DMODEL,
                                                 ln2_b + i * DMODEL, ybf);
        gemm_pipe<128, 64, 32, 3, 1, 0, 0, 1, 0>
            <<<dim3(2048 / 64, NROWS / 128), 256, 0, stream>>>(
            ybf, w1_t, bff1 + i * FFD, nullptr, ffmidb, nullptr, 2048, 512);
        gemm_pipe<128, 64, 32, 3, 0, 0, 0, 1, 0>
            <<<dim3(512 / 64, NROWS / 128), 256, 0, stream>>>(
            ffmidb, w2_t, bff2 + i * DMODEL, nullptr, pFF2, nullptr, 512, 2048);
    }
    add_kernel<<<4096, 256, 0, stream>>>(h, pFF2);
}

// Round 21
// 694.580 us; speedup vs baseline: 1.1848x; 1.0327x over previous
//
#include <hip/hip_runtime.h>
#include <math.h>

#define DEPTH 4
#define DMODEL 512
#define DH 64
#define MF 256
#define FFD 2048
#define SEQN 4096
#define NROWS 8192

typedef __bf16 bf16_t;
typedef bf16_t bf16x8 __attribute__((ext_vector_type(8)));
typedef bf16_t bf16x4 __attribute__((ext_vector_type(4)));
typedef bf16_t bf16x2 __attribute__((ext_vector_type(2)));
typedef float f32x4v __attribute__((ext_vector_type(4)));

static constexpr float DN = 0.35355339059327373f;   // 64^-0.25
static constexpr float RATIO = 0.0625f;             // 256^-0.5
static constexpr float EPSK = 1e-4f;

__device__ __forceinline__ float gelu_fast(float x) {
    float z2 = x * (1.5957691216f + 0.0713548162f * x * x);
    return x / (1.0f + __expf(-z2));
}

#define AS1(p) ((const __attribute__((address_space(1))) void*)(p))
#define AS3(p) ((__attribute__((address_space(3))) void*)(p))

template <int N> __device__ __forceinline__ void wait_vmcnt() {
    if constexpr (N == 0) asm volatile("s_waitcnt vmcnt(0)" ::: "memory");
    else if constexpr (N == 1) asm volatile("s_waitcnt vmcnt(1)" ::: "memory");
    else if constexpr (N == 2) asm volatile("s_waitcnt vmcnt(2)" ::: "memory");
    else if constexpr (N == 3) asm volatile("s_waitcnt vmcnt(3)" ::: "memory");
    else if constexpr (N == 4) asm volatile("s_waitcnt vmcnt(4)" ::: "memory");
    else if constexpr (N == 5) asm volatile("s_waitcnt vmcnt(5)" ::: "memory");
    else if constexpr (N == 6) asm volatile("s_waitcnt vmcnt(6)" ::: "memory");
    else if constexpr (N == 8) asm volatile("s_waitcnt vmcnt(8)" ::: "memory");
    else asm volatile("s_waitcnt vmcnt(12)" ::: "memory");
}

// ---------------- LayerNorm -> bf16 (no residual; src may be x or h) ----------------
__global__ __launch_bounds__(256) void ln_kernel(const float* __restrict__ h,
                                                 const float* __restrict__ g,
                                                 const float* __restrict__ b,
                                                 bf16_t* __restrict__ y) {
    int row = blockIdx.x, tid = threadIdx.x;
    const float* hr = h + (size_t)row * DMODEL;
    float v0 = hr[tid], v1 = hr[tid + 256];
    __shared__ float s_sum[256], s_sq[256];
    s_sum[tid] = v0 + v1;
    s_sq[tid] = v0 * v0 + v1 * v1;
    __syncthreads();
    for (int off = 128; off > 0; off >>= 1) {
        if (tid < off) { s_sum[tid] += s_sum[tid + off]; s_sq[tid] += s_sq[tid + off]; }
        __syncthreads();
    }
    float mu = s_sum[0] * (1.0f / DMODEL);
    float var = s_sq[0] * (1.0f / DMODEL) - mu * mu;
    float rstd = rsqrtf(var + 1e-5f);
    bf16_t* yr = y + (size_t)row * DMODEL;
    yr[tid]       = (bf16_t)((v0 - mu) * rstd * g[tid] + b[tid]);
    yr[tid + 256] = (bf16_t)((v1 - mu) * rstd * g[tid + 256] + b[tid + 256]);
}

// ---------------- fused: hout = hin + P (bf16); LayerNorm -> bf16 ----------------
__global__ __launch_bounds__(256) void ln_add_kernel(const float* __restrict__ hin,
                                                     float* __restrict__ hout,
                                                     const bf16_t* __restrict__ p,
                                                     const float* __restrict__ g,
                                                     const float* __restrict__ b,
                                                     bf16_t* __restrict__ y) {
    int row = blockIdx.x, tid = threadIdx.x;
    const float* hr = hin + (size_t)row * DMODEL;
    const bf16_t* pr = p + (size_t)row * DMODEL;
    float2 hv = *(const float2*)(hr + 2 * tid);
    bf16x2 pv = *(const bf16x2*)(pr + 2 * tid);
    float v0 = hv.x + (float)pv[0];
    float v1 = hv.y + (float)pv[1];
    float2 outv; outv.x = v0; outv.y = v1;
    *(float2*)(hout + (size_t)row * DMODEL + 2 * tid) = outv;
    __shared__ float s_sum[256], s_sq[256];
    s_sum[tid] = v0 + v1;
    s_sq[tid] = v0 * v0 + v1 * v1;
    __syncthreads();
    for (int off = 128; off > 0; off >>= 1) {
        if (tid < off) { s_sum[tid] += s_sum[tid + off]; s_sq[tid] += s_sq[tid + off]; }
        __syncthreads();
    }
    float mu = s_sum[0] * (1.0f / DMODEL);
    float var = s_sq[0] * (1.0f / DMODEL) - mu * mu;
    float rstd = rsqrtf(var + 1e-5f);
    bf16x2 ov;
    ov[0] = (bf16_t)((v0 - mu) * rstd * g[2 * tid] + b[2 * tid]);
    ov[1] = (bf16_t)((v1 - mu) * rstd * g[2 * tid + 1] + b[2 * tid + 1]);
    *(bf16x2*)(y + (size_t)row * DMODEL + 2 * tid) = ov;
}

// ---------------- tail: h += P (bf16) ----------------
__global__ __launch_bounds__(256) void add_kernel(float* __restrict__ h,
                                                  const bf16_t* __restrict__ p) {
    size_t i = ((size_t)blockIdx.x * 256 + threadIdx.x) * 4;
    float4 hv = *(const float4*)(h + i);
    bf16x4 pv = *(const bf16x4*)(p + i);
    hv.x += (float)pv[0]; hv.y += (float)pv[1];
    hv.z += (float)pv[2]; hv.w += (float)pv[3];
    *(float4*)(h + i) = hv;
}

// ---------------- weight transpose+convert; blockIdx.y = layer offset ----------------
__global__ __launch_bounds__(256) void wconv_all(const float* __restrict__ Wqkv,
                                                 const float* __restrict__ Wo,
                                                 const float* __restrict__ Wff1,
                                                 const float* __restrict__ Wff2,
                                                 bf16_t* __restrict__ wslot) {
    __shared__ float t[32][33];
    int layer = blockIdx.y;
    int bid = blockIdx.x;
    const float* W; bf16_t* Wt; int K, N, nx, lb;
    bf16_t* slot = wslot + (size_t)layer * 3407872;
    if (bid < 768)       { W = Wqkv + (size_t)layer * 786432;  Wt = slot;           K = 512;  N = 1536; nx = 48; lb = bid; }
    else if (bid < 1024) { W = Wo   + (size_t)layer * 262144;  Wt = slot + 786432;  K = 512;  N = 512;  nx = 16; lb = bid - 768; }
    else if (bid < 2048) { W = Wff1 + (size_t)layer * 1048576; Wt = slot + 1048576; K = 512;  N = 2048; nx = 64; lb = bid - 1024; }
    else                 { W = Wff2 + (size_t)layer * 1048576; Wt = slot + 2097152; K = 2048; N = 512;  nx = 16; lb = bid - 2048; }
    int n0 = (lb % nx) * 32, k0 = (lb / nx) * 32;
    int tx = threadIdx.x & 31, ty = threadIdx.x >> 5;
#pragma unroll
    for (int i = 0; i < 32; i += 8)
        t[ty + i][tx] = W[(size_t)(k0 + ty + i) * N + n0 + tx];
    __syncthreads();
#pragma unroll
    for (int i = 0; i < 32; i += 8)
        Wt[(size_t)(n0 + ty + i) * K + k0 + tx] = (bf16_t)t[tx][ty + i];
}

// ---------------- proj -> bf16 ----------------
__global__ __launch_bounds__(256) void pconv_kernel(const float* __restrict__ proj,
                                                    bf16_t* __restrict__ projb) {
    int i = (blockIdx.x * 256 + threadIdx.x) * 4;
    float4 v = *(const float4*)(proj + i);
    bf16x4 o;
    o[0] = (bf16_t)v.x; o[1] = (bf16_t)v.y; o[2] = (bf16_t)v.z; o[3] = (bf16_t)v.w;
    *(bf16x4*)(projb + i) = o;
}

// ---------------- 128x64 BK=32 P=3 pipelined MFMA GEMM, hoisted addressing ----------------
template <int BM, int BN, int BK, int P, int ACT, int RES, int WF, int WB, int QKVE>
__global__ __launch_bounds__(256) void gemm_pipe(const bf16_t* __restrict__ A,
                                                 const bf16_t* __restrict__ Bt,
                                                 const float* __restrict__ bias,
                                                 float* __restrict__ Cf,
                                                 bf16_t* __restrict__ Cb,
                                                 bf16_t* __restrict__ Vt,
                                                 int N, int K) {
    static_assert(BK == 32, "BK fixed at 32 (KS==1)");
    constexpr int MR = BM / 2 / 16;
    constexpr int NR = BN / 2 / 16;
    constexpr int CH = BK / 8;
    constexpr int SWZ = CH - 1;
    constexpr int TILE = (BM + BN) * BK;
    constexpr int L = TILE / 8 / 256;
    __shared__ __attribute__((aligned(16))) bf16_t smem[P * TILE];
    int tid = threadIdx.x;
    int wv = tid >> 6, ln = tid & 63;
    int gx = gridDim.x;
    int lin = blockIdx.y * gx + blockIdx.x;
    int per = (gx * gridDim.y) >> 3;
    int orig = (lin & 7) * per + (lin >> 3);
    int m0 = (orig / gx) * BM, n0 = (orig % gx) * BN;
    int wr = (wv >> 1) * (MR * 16), wc = (wv & 1) * (NR * 16);
    int lr = ln & 15, kq8 = ln >> 4;
    int nsteps = K / BK;

    const bf16_t* gsrc[L];
    int ldst[L];
#pragma unroll
    for (int i = 0; i < L; i++) {
        int c = i * 256 + tid;
        int cb = i * 256 + (tid & ~63);
        bool inA = (c < BM * CH);
        int cc = inA ? c : c - BM * CH;
        int row = cc / CH, ch = cc % CH;
        const bf16_t* mat = inA ? A : Bt;
        int r0 = inA ? m0 : n0;
        int chs = ch ^ ((row ^ (row >> 2)) & SWZ);
        gsrc[i] = mat + (size_t)(r0 + row) * K + chs * 8;
        ldst[i] = cb * 8;
    }
    auto stage = [&](int tile, int sb) {
        int k0 = tile * BK;
        bf16_t* dst = smem + sb * TILE;
#pragma unroll
        for (int i = 0; i < L; i++)
            __builtin_amdgcn_global_load_lds(AS1(gsrc[i] + k0), AS3(dst + ldst[i]), 16, 0, 0);
    };

    int aoff[MR], boff[NR];
#pragma unroll
    for (int m = 0; m < MR; m++) {
        int row = wr + m * 16 + lr;
        aoff[m] = (row * CH + (kq8 ^ ((row ^ (row >> 2)) & SWZ))) * 8;
    }
#pragma unroll
    for (int n = 0; n < NR; n++) {
        int row = wc + n * 16 + lr;
        boff[n] = BM * BK + (row * CH + (kq8 ^ ((row ^ (row >> 2)) & SWZ))) * 8;
    }

    f32x4v acc[MR][NR] = {};
#pragma unroll
    for (int p = 0; p < P - 1; ++p) stage(p, p);

    int cur = 0;
    for (int t = 0; t < nsteps; ++t) {
        int rem = nsteps - 1 - t;
        if (rem >= P - 2) wait_vmcnt<(P - 2) * L>();
        else if constexpr (P >= 4) {
            if (rem == 1) wait_vmcnt<L>(); else wait_vmcnt<0>();
        } else wait_vmcnt<0>();
        __builtin_amdgcn_s_barrier();
        asm volatile("" ::: "memory");
        if (t + P - 1 < nsteps) {
            int sb = cur - 1; if (sb < 0) sb = P - 1;
            stage(t + P - 1, sb);
        }
        const bf16_t* base = smem + cur * TILE;
        bf16x8 af[MR], bfr[NR];
#pragma unroll
        for (int m = 0; m < MR; m++) af[m] = *(const bf16x8*)&base[aoff[m]];
#pragma unroll
        for (int n = 0; n < NR; n++) bfr[n] = *(const bf16x8*)&base[boff[n]];
        __builtin_amdgcn_s_setprio(1);
#pragma unroll
        for (int m = 0; m < MR; m++)
#pragma unroll
            for (int n = 0; n < NR; n++)
                acc[m][n] = __builtin_amdgcn_mfma_f32_16x16x32_bf16(af[m], bfr[n], acc[m][n], 0, 0, 0);
        __builtin_amdgcn_s_setprio(0);
        cur = (cur + 1 == P) ? 0 : cur + 1;
    }
    int rq = (ln >> 4) * 4;
    if (WB || QKVE) {
        __syncthreads();
        bf16_t* T = smem;
        constexpr int S = BN + 8;
#pragma unroll
        for (int n = 0; n < NR; n++) {
            int col = wc + n * 16 + lr;
            float bcol = bias[n0 + col];
#pragma unroll
            for (int m = 0; m < MR; m++) {
#pragma unroll
                for (int r = 0; r < 4; r++) {
                    int row = wr + m * 16 + rq + r;
                    float v = acc[m][n][r] + bcol;
                    if (ACT == 1) v = gelu_fast(v);
                    int cs = (col & 7) | ((((col >> 3) ^ (row >> 3)) & (BN / 8 - 1)) << 3);
                    T[row * S + cs] = (bf16_t)v;
                }
            }
        }
        __syncthreads();
        if (!QKVE || n0 < 1024) {
            int ldc = QKVE ? 1024 : N;
#pragma unroll
            for (int i = 0; i < BM * BN / 8 / 256; i++) {
                int e = i * 2048 + tid * 8;
                int row = e / BN, c0 = e % BN;
                int ch = ((c0 >> 3) ^ (row >> 3)) & (BN / 8 - 1);
                bf16x8 v = *(const bf16x8*)&T[row * S + ch * 8];
                *(bf16x8*)&Cb[(size_t)(m0 + row) * ldc + n0 + c0] = v;
            }
        } else {
#pragma unroll
            for (int i = 0; i < BM * BN / 8 / 256; i++) {
                int u = i * 256 + tid;
                int d = u & (BN - 1), nb8 = (u / BN) * 8;
                bf16x8 v;
#pragma unroll
                for (int j = 0; j < 8; j++) {
                    int row = nb8 + j;
                    int cs = (d & 7) | ((((d >> 3) ^ (row >> 3)) & (BN / 8 - 1)) << 3);
                    v[j] = T[row * S + cs];
                }
                int gcol = n0 + d;
                int hh2 = (gcol >> 6) & 7, dd2 = gcol & 63;
                int grow = m0 + nb8;
                int bb = grow >> 12, nn = grow & 4095;
                *(bf16x8*)&Vt[(((size_t)bb * 8 + hh2) * 64 + dd2) * 4096 + nn] = v;
            }
        }
    } else {
#pragma unroll
        for (int n = 0; n < NR; n++) {
            int col = n0 + wc + n * 16 + lr;
            float bcol = bias[col];
#pragma unroll
            for (int m = 0; m < MR; m++) {
#pragma unroll
                for (int r = 0; r < 4; r++) {
                    int row = m0 + wr + m * 16 + rq + r;
                    float v = acc[m][n][r] + bcol;
                    if (ACT == 1) v = gelu_fast(v);
                    size_t idx = (size_t)row * N + col;
                    if (RES) Cf[idx] += v;
                    else Cf[idx] = v;
                }
            }
        }
    }
}

// ---------------- fused K-feature + PV kernel ----------------
// Per block (bh, tile of 128 n): dd = K@projT (MFMA), kp = exp(...), ksum partials,
// then per 128-m_feat half: LDS-transpose kp -> T[m][n], PV MFMA T @ V -> ctx partials.
// Eliminates KPt global round-trip and the separate ctx_gemm kernel.
__global__ __launch_bounds__(256) void feat_kernel(const bf16_t* __restrict__ qkvb,
                                                   const bf16_t* __restrict__ projb,
                                                   const bf16_t* __restrict__ Vt,
                                                   float* __restrict__ ctx_part,
                                                   float* __restrict__ ksum_part) {
    int bid = blockIdx.x;
    int bh = bid >> 5, tile = bid & 31;
    int b = bh >> 3, hh = bh & 7;
    int tid = threadIdx.x, wv = tid >> 6, ln = tid & 63;
    __shared__ __attribute__((aligned(16))) bf16_t AsBs[128 * 64 + 256 * 64];
    __shared__ __attribute__((aligned(16))) bf16_t Vs[64 * 128];
    bf16_t* As = AsBs;
    bf16_t* Bs = AsBs + 128 * 64;
    __shared__ float diag_s[128];
    __shared__ float ksp_s[256];
    int n0 = tile * 128;
    int qoff = 512 + hh * 64;
    int lrow8 = ln >> 3;
    int lchunk = ((ln & 7) ^ (lrow8 & 7)) * 8;
    // stage K tile (128 x 64)
#pragma unroll
    for (int i = 0; i < 4; i++) {
        int e = wv * 4 + i;
        size_t src = (size_t)(b * SEQN + n0 + e * 8 + lrow8) * 1024 + qoff + lchunk;
        __builtin_amdgcn_global_load_lds(AS1(qkvb + src), AS3(&As[e * 512]), 16, 0, 0);
    }
    // stage proj (256 x 64)
#pragma unroll
    for (int i = 0; i < 8; i++) {
        int e = wv * 8 + i;
        size_t src = (size_t)(e * 8 + lrow8) * 64 + lchunk;
        __builtin_amdgcn_global_load_lds(AS1(projb + src), AS3(&Bs[e * 512]), 16, 0, 0);
    }
    // stage V tile (64 d x 128 n) from Vt[bh*64+d][n], chunk-swizzled by (row & 15)
#pragma unroll
    for (int i = 0; i < 4; i++) {
        int c = i * 256 + tid;
        int cb = i * 256 + (tid & ~63);
        int row = c >> 4, ch = c & 15;
        int chs = ch ^ (row & 15);
        size_t src = (size_t)(bh * 64 + row) * 4096 + n0 + chs * 8;
        __builtin_amdgcn_global_load_lds(AS1(Vt + src), AS3(&Vs[cb * 8]), 16, 0, 0);
    }
    __syncthreads();
    if (tid < 128) {
        float s = 0.f;
#pragma unroll
        for (int c = 0; c < 8; c++) {
            bf16x8 v = *(const bf16x8*)&As[tid * 64 + ((c ^ (tid & 7)) * 8)];
#pragma unroll
            for (int j = 0; j < 8; j++) { float f = (float)v[j]; s += f * f; }
        }
        diag_s[tid] = s * (0.5f * DN * DN);
    }
    int wr = (wv >> 1) * 64, wc = (wv & 1) * 128;
    int lr = ln & 15, kg = ln >> 4, rq = kg * 4;
    f32x4v acc[4][8] = {};
#pragma unroll
    for (int ks = 0; ks < 2; ks++) {
        int g = ks * 4 + kg;
        bf16x8 af[4], bfv[8];
#pragma unroll
        for (int m = 0; m < 4; m++) {
            int row = wr + m * 16 + lr;
            af[m] = *(const bf16x8*)&As[row * 64 + ((g ^ (row & 7)) * 8)];
        }
#pragma unroll
        for (int n = 0; n < 8; n++) {
            int row = wc + n * 16 + lr;
            bfv[n] = *(const bf16x8*)&Bs[row * 64 + ((g ^ (row & 7)) * 8)];
        }
#pragma unroll
        for (int m = 0; m < 4; m++)
#pragma unroll
            for (int n = 0; n < 8; n++)
                acc[m][n] = __builtin_amdgcn_mfma_f32_16x16x32_bf16(af[m], bfv[n], acc[m][n], 0, 0, 0);
    }
    __syncthreads();   // diag_s visible; As/Bs reads done
    // kp in-place; ksum partials
    float sj[8] = {};
#pragma unroll
    for (int m = 0; m < 4; m++) {
#pragma unroll
        for (int n = 0; n < 8; n++) {
#pragma unroll
            for (int r = 0; r < 4; r++) {
                int row = wr + m * 16 + rq + r;
                float val = RATIO * (__expf(acc[m][n][r] * DN - diag_s[row]) + EPSK);
                acc[m][n][r] = val;
                sj[n] += val;
            }
        }
    }
#pragma unroll
    for (int n = 0; n < 8; n++) {
        sj[n] += __shfl_xor(sj[n], 16);
        sj[n] += __shfl_xor(sj[n], 32);
    }
    if (wv < 2 && ln < 16) {
#pragma unroll
        for (int n = 0; n < 8; n++) ksp_s[wc + n * 16 + ln] = sj[n];
    }
    __syncthreads();
    if (wv >= 2 && ln < 16) {
#pragma unroll
        for (int n = 0; n < 8; n++) ksp_s[wc + n * 16 + ln] += sj[n];
    }
    __syncthreads();   // ksp done; AsBs free for reuse as T
    ksum_part[(size_t)bid * 256 + tid] = ksp_s[tid];
    // per 128-m_feat half: transpose kp into T[m][n] then PV: T @ Vs -> ctx partial
    bf16_t* T = AsBs;                    // 128 x 136 bf16
    float* cpb = ctx_part + (size_t)(tile * 16 + bh) * 16384;   // [256 m][64 d]
#pragma unroll
    for (int hf = 0; hf < 2; hf++) {
        if ((wv & 1) == hf) {
#pragma unroll
            for (int n = 0; n < 8; n++) {
                int mm = n * 16 + lr;            // m_feat within half
#pragma unroll
                for (int m = 0; m < 4; m++) {
                    int nnb = wr + m * 16 + rq;  // n (multiple of 4)
                    bf16x4 v;
#pragma unroll
                    for (int r = 0; r < 4; r++) v[r] = (bf16_t)acc[m][n][r];
                    *(bf16x4*)&T[mm * 136 + nnb] = v;
                }
            }
        }
        __syncthreads();
        // PV: A = T[m_feat][n] (K = n = 128), B = V[n][d] from Vs[d][n] swizzled
        f32x4v accp[2][4] = {};
#pragma unroll
        for (int ks = 0; ks < 4; ks++) {
            int g = ks * 4 + kg;
            bf16x8 apv[2], bpv[4];
#pragma unroll
            for (int mt = 0; mt < 2; mt++) {
                int rowm = (wv * 2 + mt) * 16 + lr;
                apv[mt] = *(const bf16x8*)&T[rowm * 136 + g * 8];
            }
#pragma unroll
            for (int dt = 0; dt < 4; dt++) {
                int d = dt * 16 + lr;
                bpv[dt] = *(const bf16x8*)&Vs[d * 128 + ((g ^ (d & 15)) * 8)];
            }
#pragma unroll
            for (int mt = 0; mt < 2; mt++)
#pragma unroll
                for (int dt = 0; dt < 4; dt++)
                    accp[mt][dt] = __builtin_amdgcn_mfma_f32_16x16x32_bf16(apv[mt], bpv[dt], accp[mt][dt], 0, 0, 0);
        }
        // write ctx partial for this half
#pragma unroll
        for (int mt = 0; mt < 2; mt++) {
#pragma unroll
            for (int r = 0; r < 4; r++) {
                int mfeat = hf * 128 + (wv * 2 + mt) * 16 + rq + r;
#pragma unroll
                for (int dt = 0; dt < 4; dt++)
                    cpb[(size_t)mfeat * 64 + dt * 16 + lr] = accp[mt][dt][r];
            }
        }
        __syncthreads();   // T fully consumed before next half overwrites
    }
}

// ---------------- ctx reduce (32 partials): grid = 16 bh x 16 chunks ----------------
__global__ __launch_bounds__(256) void ctx_reduce_kernel(const float* __restrict__ part,
                                                         const float* __restrict__ ksum_part,
                                                         bf16_t* __restrict__ ctx_t,
                                                         float* __restrict__ ksum) {
    int bh = blockIdx.x >> 4;
    int chunk = blockIdx.x & 15;
    for (int it = 0; it < 4; it++) {
        int idx = (chunk * 4 + it) * 256 + threadIdx.x;
        int m = idx >> 6, d = idx & 63;
        float s = 0.f;
#pragma unroll
        for (int kc = 0; kc < 32; kc++)
            s += part[(size_t)(kc * 16 + bh) * 16384 + idx];
        ctx_t[((size_t)bh * 64 + d) * MF + m] = (bf16_t)s;
    }
    if (chunk == 0) {
        float s = 0.f;
#pragma unroll
        for (int t = 0; t < 32; t++)
            s += ksum_part[((size_t)bh * 32 + t) * 256 + threadIdx.x];
        ksum[bh * MF + threadIdx.x] = s;
    }
}

// ---------------- fused Q-side: q-features + dinv + (qp@ctx)*dinv -> abuf ----------------
__global__ __launch_bounds__(256) void qfused_kernel(const bf16_t* __restrict__ qkvb,
                                                     const bf16_t* __restrict__ projb,
                                                     const bf16_t* __restrict__ ctx_t,
                                                     const float* __restrict__ ksumb,
                                                     bf16_t* __restrict__ abuf) {
    int bid = blockIdx.x;
    int bh = bid >> 5, tile = bid & 31;
    int b = bh >> 3, hh = bh & 7;
    int tid = threadIdx.x, wv = tid >> 6, ln = tid & 63;
    __shared__ __attribute__((aligned(16))) bf16_t Qs[128 * 64];
    __shared__ __attribute__((aligned(16))) bf16_t Ps[256 * 64];
    __shared__ __attribute__((aligned(16))) bf16_t Cs[64 * 256];
    __shared__ float diag_s[128];
    __shared__ float dsum_s[128];
    int n0 = tile * 128;
    int lrow8 = ln >> 3;
    int lchunk = ((ln & 7) ^ (lrow8 & 7)) * 8;
#pragma unroll
    for (int i = 0; i < 4; i++) {
        int e = wv * 4 + i;
        size_t src = (size_t)(b * SEQN + n0 + e * 8 + lrow8) * 1024 + hh * 64 + lchunk;
        __builtin_amdgcn_global_load_lds(AS1(qkvb + src), AS3(&Qs[e * 512]), 16, 0, 0);
    }
#pragma unroll
    for (int i = 0; i < 8; i++) {
        int e = wv * 8 + i;
        size_t src = (size_t)(e * 8 + lrow8) * 64 + lchunk;
        __builtin_amdgcn_global_load_lds(AS1(projb + src), AS3(&Ps[e * 512]), 16, 0, 0);
    }
#pragma unroll
    for (int i = 0; i < 8; i++) {
        int c = i * 256 + tid;
        int cb = i * 256 + (tid & ~63);
        int crow = c >> 5, cch = c & 31;
        size_t src = ((size_t)bh * 64 + crow) * 256 + (size_t)(cch ^ (crow & 7)) * 8;
        __builtin_amdgcn_global_load_lds(AS1(ctx_t + src), AS3(Cs + (size_t)cb * 8), 16, 0, 0);
    }
    int wr = (wv >> 1) * 64, wc = (wv & 1) * 128;
    int lr = ln & 15, kg = ln >> 4, rq = kg * 4;
    float ksum_r[8];
#pragma unroll
    for (int n = 0; n < 8; n++) ksum_r[n] = ksumb[bh * MF + wc + n * 16 + lr];
    __syncthreads();
    if (tid < 128) {
        float s = 0.f;
#pragma unroll
        for (int c = 0; c < 8; c++) {
            bf16x8 v = *(const bf16x8*)&Qs[tid * 64 + ((c ^ (tid & 7)) * 8)];
#pragma unroll
            for (int j = 0; j < 8; j++) { float f = (float)v[j]; s += f * f; }
        }
        diag_s[tid] = s * (0.5f * DN * DN);
    }
    f32x4v acc[4][8] = {};
#pragma unroll
    for (int ks = 0; ks < 2; ks++) {
        int g = ks * 4 + kg;
        bf16x8 af[4], bfv[8];
#pragma unroll
        for (int m = 0; m < 4; m++) {
            int row = wr + m * 16 + lr;
            af[m] = *(const bf16x8*)&Qs[row * 64 + ((g ^ (row & 7)) * 8)];
        }
#pragma unroll
        for (int n = 0; n < 8; n++) {
            int row = wc + n * 16 + lr;
            bfv[n] = *(const bf16x8*)&Ps[row * 64 + ((g ^ (row & 7)) * 8)];
        }
#pragma unroll
        for (int m = 0; m < 4; m++)
#pragma unroll
            for (int n = 0; n < 8; n++)
                acc[m][n] = __builtin_amdgcn_mfma_f32_16x16x32_bf16(af[m], bfv[n], acc[m][n], 0, 0, 0);
    }
    __syncthreads();
    float dsum_p[4][4];
#pragma unroll
    for (int m = 0; m < 4; m++) {
#pragma unroll
        for (int r = 0; r < 4; r++) {
            int row = wr + m * 16 + rq + r;
            float dg = diag_s[row];
            float ds = 0.f;
#pragma unroll
            for (int n = 0; n < 8; n++) {
                float val = RATIO * (__expf(acc[m][n][r] * DN - dg) + EPSK);
                acc[m][n][r] = val;
                ds += val * ksum_r[n];
            }
            dsum_p[m][r] = ds;
        }
    }
#pragma unroll
    for (int m = 0; m < 4; m++)
#pragma unroll
        for (int r = 0; r < 4; r++) {
#pragma unroll
            for (int mask = 1; mask < 16; mask <<= 1)
                dsum_p[m][r] += __shfl_xor(dsum_p[m][r], mask);
        }
    if ((wv & 1) == 0 && lr == 0) {
#pragma unroll
        for (int m = 0; m < 4; m++)
#pragma unroll
            for (int r = 0; r < 4; r++)
                dsum_s[wr + m * 16 + rq + r] = dsum_p[m][r];
    }
    __syncthreads();
    if ((wv & 1) == 1 && lr == 0) {
#pragma unroll
        for (int m = 0; m < 4; m++)
#pragma unroll
            for (int r = 0; r < 4; r++) {
                int row = wr + m * 16 + rq + r;
                dsum_s[row] = 1.0f / (dsum_s[row] + dsum_p[m][r]);
            }
    }
    __syncthreads();
    f32x4v acc_o[4][2] = {};
#pragma unroll
    for (int h = 0; h < 2; h++) {
        if ((wv & 1) == h) {
#pragma unroll
            for (int m = 0; m < 4; m++)
#pragma unroll
                for (int n = 0; n < 8; n++)
#pragma unroll
                    for (int r = 0; r < 4; r++) {
                        int row = wr + m * 16 + rq + r;
                        int ml = n * 16 + lr;
                        Ps[row * 128 + (((ml >> 3) ^ (row & 7)) * 8) + (ml & 7)] =
                            (bf16_t)acc[m][n][r];
                    }
        }
        __syncthreads();
#pragma unroll
        for (int ku = 0; ku < 4; ku++) {
            int g = ku * 4 + kg;
            bf16x8 af[4], bfv[2];
#pragma unroll
            for (int m = 0; m < 4; m++) {
                int row = wr + m * 16 + lr;
                af[m] = *(const bf16x8*)&Ps[row * 128 + ((g ^ (row & 7)) * 8)];
            }
#pragma unroll
            for (int n = 0; n < 2; n++) {
                int rowd = (wv & 1) * 32 + n * 16 + lr;
                int ch = (h * 16 + g) ^ (rowd & 7);
                bfv[n] = *(const bf16x8*)&Cs[(rowd * 32 + ch) * 8];
            }
#pragma unroll
            for (int m = 0; m < 4; m++)
#pragma unroll
                for (int n = 0; n < 2; n++)
                    acc_o[m][n] = __builtin_amdgcn_mfma_f32_16x16x32_bf16(af[m], bfv[n], acc_o[m][n], 0, 0, 0);
        }
        __syncthreads();
    }
#pragma unroll
    for (int m = 0; m < 4; m++) {
#pragma unroll
        for (int r = 0; r < 4; r++) {
            int rowl = wr + m * 16 + rq + r;
            float di = dsum_s[rowl];
            size_t obase = ((size_t)(b * SEQN + n0 + rowl)) * DMODEL + hh * 64;
#pragma unroll
            for (int n = 0; n < 2; n++) {
                int d = (wv & 1) * 32 + n * 16 + lr;
                abuf[obase + d] = (bf16_t)(acc_o[m][n][r] * di);
            }
        }
    }
}

extern "C" void kernel_launch(void* const* d_in, const int* in_sizes, int n_in,
                              void* d_out, int out_size, void* d_ws, size_t ws_size,
                              hipStream_t stream) {
    const float* x     = (const float*)d_in[0];
    const float* proj  = (const float*)d_in[1];
    const float* ln1_g = (const float*)d_in[2];
    const float* ln1_b = (const float*)d_in[3];
    const float* Wqkv  = (const float*)d_in[4];
    const float* bqkv  = (const float*)d_in[5];
    const float* Wo    = (const float*)d_in[6];
    const float* bo    = (const float*)d_in[7];
    const float* ln2_g = (const float*)d_in[8];
    const float* ln2_b = (const float*)d_in[9];
    const float* Wff1  = (const float*)d_in[10];
    const float* bff1  = (const float*)d_in[11];
    const float* Wff2  = (const float*)d_in[12];
    const float* bff2  = (const float*)d_in[13];

    float* h = (float*)d_out;
    char* ws = (char*)d_ws;
    bf16_t* ybf   = (bf16_t*)(ws);               // 8 MB
    bf16_t* pWo   = (bf16_t*)(ws + 8388608);     // 8 MB
    bf16_t* pFF2  = (bf16_t*)(ws + 16777216);    // 8 MB
    bf16_t* qkvb  = (bf16_t*)(ws + 33554432);    // 16 MB
    bf16_t* abufb = (bf16_t*)(ws + 50331648);    // 8 MB
    float*  ctx_part = (float*)(ws + 58720256);  // 32 MB -> ends 92274688
    bf16_t* ffmidb   = (bf16_t*)(ws + 50331648); // 32 MB (alias; disjoint live range)
    bf16_t* Vt    = (bf16_t*)(ws + 92274688);    // 8 MB -> ends 100663296
    bf16_t* projb = (bf16_t*)(ws + 100663296);   // 128 KB
    bf16_t* ctx_t = (bf16_t*)(ws + 100794368);   // 512 KB
    float*  ksumb = (float*)(ws + 101318656);    // 16 KB
    float*  ksum_part = (float*)(ws + 101335040);// 512 KB
    bf16_t* wbase = (bf16_t*)(ws + 101859328);   // 4 x 6.5 MB
    const size_t WSLOT = 3407872;
    bool hoist = ws_size >= (size_t)101859328 + 4 * 6815744;

    pconv_kernel<<<64, 256, 0, stream>>>(proj, projb);
    if (hoist)
        wconv_all<<<dim3(3072, 4), 256, 0, stream>>>(Wqkv, Wo, Wff1, Wff2, wbase);

    for (int i = 0; i < DEPTH; i++) {
        const bf16_t* pj = projb + (size_t)i * MF * DH;
        if (!hoist)
            wconv_all<<<dim3(3072, 1), 256, 0, stream>>>(
                Wqkv + (size_t)i * 786432, Wo + (size_t)i * 262144,
                Wff1 + (size_t)i * 1048576, Wff2 + (size_t)i * 1048576, wbase);
        bf16_t* wl = wbase + (hoist ? (size_t)i * WSLOT : 0);
        bf16_t* wq_t = wl;
        bf16_t* wo_t = wl + 786432;
        bf16_t* w1_t = wl + 1048576;
        bf16_t* w2_t = wl + 2097152;

        if (i == 0)
            ln_kernel<<<NROWS, 256, 0, stream>>>(x, ln1_g, ln1_b, ybf);
        else
            ln_add_kernel<<<NROWS, 256, 0, stream>>>(h, h, pFF2, ln1_g + i * DMODEL,
                                                     ln1_b + i * DMODEL, ybf);
        gemm_pipe<128, 64, 32, 3, 0, 0, 0, 0, 1>
            <<<dim3(1536 / 64, NROWS / 128), 256, 0, stream>>>(
            ybf, wq_t, bqkv + i * 1536, nullptr, qkvb, Vt, 1536, 512);
        feat_kernel<<<512, 256, 0, stream>>>(qkvb, pj, Vt, ctx_part, ksum_part);
        ctx_reduce_kernel<<<256, 256, 0, stream>>>(ctx_part, ksum_part, ctx_t, ksumb);
        qfused_kernel<<<512, 256, 0, stream>>>(qkvb, pj, ctx_t, ksumb, abufb);
        gemm_pipe<128, 64, 32, 3, 0, 0, 0, 1, 0>
            <<<dim3(512 / 64, NROWS / 128), 256, 0, stream>>>(
            abufb, wo_t, bo + i * DMODEL, nullptr, pWo, nullptr, 512, 512);

        ln_add_kernel<<<NROWS, 256, 0, stream>>>(i == 0 ? x : h, h, pWo,
                                                 ln2_g + i * DMODEL,
                                                 ln2_b + i * DMODEL, ybf);
        gemm_pipe<128, 64, 32, 3, 1, 0, 0, 1, 0>
            <<<dim3(2048 / 64, NROWS / 128), 256, 0, stream>>>(
            ybf, w1_t, bff1 + i * FFD, nullptr, ffmidb, nullptr, 2048, 512);
        gemm_pipe<128, 64, 32, 3, 0, 0, 0, 1, 0>
            <<<dim3(512 / 64, NROWS / 128), 256, 0, stream>>>(
            ffmidb, w2_t, bff2 + i * DMODEL, nullptr, pFF2, nullptr, 512, 2048);
    }
    add_kernel<<<4096, 256, 0, stream>>>(h, pFF2);
}